// Round 15
// baseline (91.902 us; speedup 1.0000x reference)
//
#include <hip/hip_runtime.h>
#include <stdint.h>

// ---------------------------------------------------------------------------
// WindowedAttn: x(2,2048,1024) f32 -> QKV proj -> windowed causal attn (W=256)
// -> out proj. bf16 MFMA pipeline, f32 in/out.
// Round 15: gemm1 switched to 32x32x16 MFMA (k_gemm32: half the MFMA/VALU
// issue per FLOP, same LDS traffic; C/D layout per m74/m101). gemm2 <64,64>,
// attn (1-barrier static-max), prep unchanged from r14.
// ---------------------------------------------------------------------------

typedef __attribute__((ext_vector_type(8))) short bf16x8;     // 8 bf16 (4 VGPR)
typedef __attribute__((ext_vector_type(4))) float f32x4;      // MFMA C/D 16x16
typedef __attribute__((ext_vector_type(16))) float f32x16;    // MFMA C/D 32x32
typedef __attribute__((ext_vector_type(4))) unsigned int u32x4;
typedef __attribute__((ext_vector_type(4))) unsigned short u16x4;

#define DEV static __device__ __forceinline__

#define SC2 0.18033688011112042f   // 0.125 * log2(e), folded into Wq + bq

DEV unsigned short f2bf(float f) {            // f32 -> bf16 RNE
  unsigned int u = __builtin_bit_cast(unsigned int, f);
  u += 0x7fffu + ((u >> 16) & 1u);
  return (unsigned short)(u >> 16);
}

DEV void gload_lds16(const void* g, void* l) { // 16B global -> LDS direct
  __builtin_amdgcn_global_load_lds((const __attribute__((address_space(1))) void*)g,
                                   (__attribute__((address_space(3))) void*)l,
                                   16, 0, 0);
}

// ------------- prep: x->bf16, Wqkv^T (Q cols pre-scaled), Wout^T, bias -----
__global__ __launch_bounds__(256) void k_prep(const float* __restrict__ x,
                                              const float* __restrict__ Wqkv,
                                              const float* __restrict__ Wout,
                                              const float* __restrict__ bqkv,
                                              unsigned short* __restrict__ xb,
                                              unsigned short* __restrict__ wqT,
                                              unsigned short* __restrict__ woT,
                                              float* __restrict__ bqkv_s) {
  __shared__ float t[32][33];
  const int bid = blockIdx.x, tid = threadIdx.x;
  if (bid < 4096) {
    int i = bid * 256 + tid;
    f32x4 v = ((const f32x4*)x)[i];
    u16x4 o;
    o[0] = f2bf(v[0]); o[1] = f2bf(v[1]); o[2] = f2bf(v[2]); o[3] = f2bf(v[3]);
    ((u16x4*)xb)[i] = o;
    return;
  }
  if (bid >= 8192) {                        // scaled bias (bq *= SC2)
    int i = (bid - 8192) * 256 + tid;
    if (i < 3072) bqkv_s[i] = bqkv[i] * (i < 1024 ? SC2 : 1.0f);
    return;
  }
  const float* in;
  unsigned short* out;
  int N, K, n0, k0;
  float wscale = 1.0f;
  if (bid < 7168) {                         // Wqkv: (1024,3072) -> (3072,1024)
    int tt = bid - 4096;
    in = Wqkv; out = wqT; N = 3072; K = 1024;
    n0 = (tt % 96) * 32; k0 = (tt / 96) * 32;
    if (n0 < 1024) wscale = SC2;            // Q columns pre-scaled
  } else {                                  // Wout: (1024,1024) -> (1024,1024)
    int tt = bid - 7168;
    in = Wout; out = woT; N = 1024; K = 1024;
    n0 = (tt % 32) * 32; k0 = (tt / 32) * 32;
  }
  const int tx = tid & 31, ty = tid >> 5;   // 32 x 8
#pragma unroll
  for (int i = 0; i < 4; ++i)
    t[ty + i * 8][tx] = in[(size_t)(k0 + ty + i * 8) * N + n0 + tx];
  __syncthreads();
#pragma unroll
  for (int i = 0; i < 4; ++i)
    out[(size_t)(n0 + ty + i * 8) * K + k0 + tx] = f2bf(t[tx][ty + i * 8] * wscale);
}

// -------- gemm1: 128x192 tile, BK=32, 2-buf, 32x32x16 MFMA -----------------
// C[M][N] = A[M][K] @ Bt[N][K]^T + bias, bf16 out + fused V^T write.
// 4 waves (2x2); wave tile 64x96 = 2(tm) x 3(tn) 32x32 acc tiles.
// Per iter: ONE __syncthreads -> stage(kt+1 -> buf^1) -> per k-half h (K=16):
// 2 A-frags + 3 B-frags (b128) -> 6 mfma_32x32x16. Same XOR swizzle as r14
// BK=32 (logical slot ks = (2h + lane>>5) ^ ((r>>1)&3), row r ^ ((r>>3)&1)).
// C/D layout (m74/m101): col = lane&31, row = (reg&3) + 8*(reg>>2) + 4*(lane>>5).
__global__ __launch_bounds__(256) void k_gemm32(const unsigned short* __restrict__ A,
                                                const unsigned short* __restrict__ Bt,
                                                const float* __restrict__ bias,
                                                unsigned short* __restrict__ C,
                                                unsigned short* __restrict__ vT,
                                                int M, int N, int K) {
  __shared__ unsigned short As[2][128 * 32];
  __shared__ unsigned short Bs[2][192 * 32];
  const int tid = threadIdx.x;
  const int lane = tid & 63, wid = tid >> 6;
  const int wr = wid >> 1, wc = wid & 1;
  const int l5 = lane >> 5, r31 = lane & 31;
  const int m0 = blockIdx.y * 128, n0 = blockIdx.x * 192;

  f32x16 acc[2][3] = {};
  const int nkt = K >> 5;

  const int rin = lane >> 2, skp = lane & 3;
  auto stage = [&](int bufi, int kt) {
#pragma unroll
    for (int c = wid; c < 20; c += 4) {     // 8 A-chunks + 12 B-chunks of 16 rows
      const int cc = (c < 8) ? c : c - 8;
      const int row_p = cc * 16 + rin;
      const int row_l = row_p ^ ((row_p >> 3) & 1);
      const int ks_l  = skp ^ ((row_p >> 1) & 3);
      if (c < 8)
        gload_lds16(A + (size_t)(m0 + row_l) * K + kt * 32 + ks_l * 8,
                    &As[bufi][cc * 512]);
      else
        gload_lds16(Bt + (size_t)(n0 + row_l) * K + kt * 32 + ks_l * 8,
                    &Bs[bufi][cc * 512]);
    }
  };

  stage(0, 0);
  for (int kt = 0; kt < nkt; ++kt) {
    __syncthreads();                        // tile-kt landed; buf^1 reads retired
    if (kt + 1 < nkt) stage((kt + 1) & 1, kt + 1);   // prefetch under compute
    const unsigned short* Ac = As[kt & 1];
    const unsigned short* Bc = Bs[kt & 1];
#pragma unroll
    for (int h = 0; h < 2; ++h) {           // two K=16 halves of BK=32
      bf16x8 af[2], bf[3];
#pragma unroll
      for (int tm = 0; tm < 2; ++tm) {
        const int r = wr * 64 + tm * 32 + r31;
        const int rr = r ^ ((r >> 3) & 1);
        const int ks = (h * 2 + l5) ^ ((r >> 1) & 3);
        af[tm] = *(const bf16x8*)&Ac[rr * 32 + ks * 8];
      }
#pragma unroll
      for (int tn = 0; tn < 3; ++tn) {
        const int r = wc * 96 + tn * 32 + r31;
        const int rr = r ^ ((r >> 3) & 1);
        const int ks = (h * 2 + l5) ^ ((r >> 1) & 3);
        bf[tn] = *(const bf16x8*)&Bc[rr * 32 + ks * 8];
      }
#pragma unroll
      for (int tm = 0; tm < 2; ++tm)
#pragma unroll
        for (int tn = 0; tn < 3; ++tn)
          acc[tm][tn] = __builtin_amdgcn_mfma_f32_32x32x16_bf16(af[tm], bf[tn],
                                                                acc[tm][tn], 0, 0, 0);
    }
  }

  // epilogue: 32x32 C/D layout col = r31, row = (reg&3) + 8*(reg>>2) + 4*l5
#pragma unroll
  for (int tn = 0; tn < 3; ++tn) {
    const int col = n0 + wc * 96 + tn * 32 + r31;
    const float bv = bias[col];
#pragma unroll
    for (int tm = 0; tm < 2; ++tm) {
      const int rowb = m0 + wr * 64 + tm * 32 + 4 * l5;
#pragma unroll
      for (int rc = 0; rc < 4; ++rc) {      // reg clusters of 4 -> rows rowb+8rc+0..3
        const int r0 = rowb + 8 * rc;
        float v0 = acc[tm][tn][rc * 4 + 0] + bv;
        float v1 = acc[tm][tn][rc * 4 + 1] + bv;
        float v2 = acc[tm][tn][rc * 4 + 2] + bv;
        float v3 = acc[tm][tn][rc * 4 + 3] + bv;
        C[(size_t)(r0 + 0) * N + col] = f2bf(v0);
        C[(size_t)(r0 + 1) * N + col] = f2bf(v1);
        C[(size_t)(r0 + 2) * N + col] = f2bf(v2);
        C[(size_t)(r0 + 3) * N + col] = f2bf(v3);
        if (col >= 2048) {                  // V third: also write transposed
          const int b = r0 >> 11;
          const int s = r0 & 2047;
          u16x4 vv;
          vv[0] = f2bf(v0); vv[1] = f2bf(v1); vv[2] = f2bf(v2); vv[3] = f2bf(v3);
          *(u16x4*)&vT[(size_t)(b * 1024 + col - 2048) * 2048 + s] = vv;
        }
      }
    }
  }
}

// -------- bf16 GEMM (16x16): 128 x BN tile, BK in {32,64}, 2-buf -----------
// Used for the out-projection: <64,64,true,false>, grid 512, 3 blk/CU.
template <int BN, int BK, bool F32OUT, bool FUSE_VT>
__global__ __launch_bounds__(256) void k_gemm(const unsigned short* __restrict__ A,
                                              const unsigned short* __restrict__ Bt,
                                              const float* __restrict__ bias,
                                              void* __restrict__ Cout,
                                              unsigned short* __restrict__ vT,
                                              int M, int N, int K) {
  constexpr int NI = BN / 32;               // B frags per wave
  constexpr int RPC = (BK == 32) ? 16 : 8;  // rows per 512-elem staging chunk
  constexpr int ACH = 128 / RPC;            // A chunks
  constexpr int NCH = (128 + BN) / RPC;     // total chunks
  __shared__ unsigned short As[2][128 * BK];
  __shared__ unsigned short Bs[2][BN * BK];
  const int tid = threadIdx.x;
  const int lane = tid & 63, wid = tid >> 6;
  const int wr = wid >> 1, wc = wid & 1;
  const int g = lane >> 4, li = lane & 15;
  const int m0 = blockIdx.y * 128, n0 = blockIdx.x * BN;

  f32x4 acc[4][NI] = {};
  const int nkt = K / BK;

  auto stage = [&](int bufi, int kt) {
#pragma unroll
    for (int c = wid; c < NCH; c += 4) {
      const unsigned short* src;
      unsigned short* dst;
      int row, sl;
      if (BK == 32) {
        const int rin = lane >> 2, skp = lane & 3;
        const int cc = (c < ACH) ? c : c - ACH;
        const int row_p = cc * 16 + rin;
        row = row_p ^ ((row_p >> 3) & 1);
        sl = skp ^ ((row_p >> 1) & 3);
        src = (c < ACH) ? A + (size_t)(m0 + row) * K + kt * 32 + sl * 8
                        : Bt + (size_t)(n0 + row) * K + kt * 32 + sl * 8;
        dst = (c < ACH) ? &As[bufi][cc * 512] : &Bs[bufi][cc * 512];
      } else {
        const int r8 = lane >> 3, sp = lane & 7;
        const int cc = (c < ACH) ? c : c - ACH;
        row = cc * 8 + r8;
        sl = sp ^ (row & 7);
        src = (c < ACH) ? A + (size_t)(m0 + row) * K + kt * 64 + sl * 8
                        : Bt + (size_t)(n0 + row) * K + kt * 64 + sl * 8;
        dst = (c < ACH) ? &As[bufi][cc * 512] : &Bs[bufi][cc * 512];
      }
      gload_lds16(src, dst);
    }
  };

  stage(0, 0);
  for (int kt = 0; kt < nkt; ++kt) {
    __syncthreads();                        // own vmcnt drained -> tile-kt visible
    if (kt + 1 < nkt) stage((kt + 1) & 1, kt + 1);   // prefetch under compute
    const unsigned short* Ac = As[kt & 1];
    const unsigned short* Bc = Bs[kt & 1];
#pragma unroll
    for (int h = 0; h < BK / 32; ++h) {
      bf16x8 af[4], bfr[NI];
#pragma unroll
      for (int mi = 0; mi < 4; ++mi) {
        const int r = wr * 64 + mi * 16 + li;
        if (BK == 32) {
          const int rr = r ^ ((r >> 3) & 1);
          const int ks = g ^ ((r >> 1) & 3);
          af[mi] = *(const bf16x8*)&Ac[rr * 32 + ks * 8];
        } else {
          const int slot = (g + h * 4) ^ (r & 7);
          af[mi] = *(const bf16x8*)&Ac[r * 64 + slot * 8];
        }
      }
#pragma unroll
      for (int ni = 0; ni < NI; ++ni) {
        const int r = wc * (BN / 2) + ni * 16 + li;
        if (BK == 32) {
          const int rr = r ^ ((r >> 3) & 1);
          const int ks = g ^ ((r >> 1) & 3);
          bfr[ni] = *(const bf16x8*)&Bc[rr * 32 + ks * 8];
        } else {
          const int slot = (g + h * 4) ^ (r & 7);
          bfr[ni] = *(const bf16x8*)&Bc[r * 64 + slot * 8];
        }
      }
#pragma unroll
      for (int mi = 0; mi < 4; ++mi)
#pragma unroll
        for (int ni = 0; ni < NI; ++ni)
          acc[mi][ni] = __builtin_amdgcn_mfma_f32_16x16x32_bf16(af[mi], bfr[ni],
                                                                acc[mi][ni], 0, 0, 0);
    }
  }

  // epilogue: C/D layout col = li, row = g*4 + reg
  float bv[NI];
#pragma unroll
  for (int ni = 0; ni < NI; ++ni) bv[ni] = bias[n0 + wc * (BN / 2) + ni * 16 + li];
#pragma unroll
  for (int mi = 0; mi < 4; ++mi) {
#pragma unroll
    for (int ni = 0; ni < NI; ++ni) {
      const int col = n0 + wc * (BN / 2) + ni * 16 + li;
      const int row0 = m0 + wr * 64 + mi * 16 + g * 4;
      float v0 = acc[mi][ni][0] + bv[ni];
      float v1 = acc[mi][ni][1] + bv[ni];
      float v2 = acc[mi][ni][2] + bv[ni];
      float v3 = acc[mi][ni][3] + bv[ni];
      if (F32OUT) {
        float* C = (float*)Cout;
        C[(size_t)(row0 + 0) * N + col] = v0;
        C[(size_t)(row0 + 1) * N + col] = v1;
        C[(size_t)(row0 + 2) * N + col] = v2;
        C[(size_t)(row0 + 3) * N + col] = v3;
      } else {
        unsigned short* C = (unsigned short*)Cout;
        C[(size_t)(row0 + 0) * N + col] = f2bf(v0);
        C[(size_t)(row0 + 1) * N + col] = f2bf(v1);
        C[(size_t)(row0 + 2) * N + col] = f2bf(v2);
        C[(size_t)(row0 + 3) * N + col] = f2bf(v3);
      }
      if (FUSE_VT && col >= 2048) {
        const int b = row0 >> 11;
        const int s = row0 & 2047;
        u16x4 vv;
        vv[0] = f2bf(v0); vv[1] = f2bf(v1); vv[2] = f2bf(v2); vv[3] = f2bf(v3);
        *(u16x4*)&vT[(size_t)(b * 1024 + col - 2048) * 2048 + s] = vv;
      }
    }
  }
}

// ---------- windowed flash attention (1 barrier/tile, static-max) ----------
__global__ __launch_bounds__(256) void k_attn3(const unsigned short* __restrict__ qkv,
                                               const unsigned short* __restrict__ vT,
                                               unsigned short* __restrict__ attn) {
  __shared__ unsigned short Ks[2][64 * 64];
  __shared__ unsigned short Vs[2][64 * 64];
  __shared__ unsigned short Ps[64 * 88];
  const int tid = threadIdx.x, lane = tid & 63, wid = tid >> 6;
  const int g = lane >> 4, li = lane & 15;
  const int bh = blockIdx.y, b = bh >> 4, h = bh & 15;
  const int q0 = blockIdx.x * 64;
  const size_t rs = 3072;
  const unsigned short* qb = qkv + (size_t)b * 2048 * rs + h * 64;
  const unsigned short* kb = qb + 1024;
  const unsigned short* vb = vT + (size_t)bh * 64 * 2048;

  const int qrow = wid * 16 + li;
  const bf16x8 qf0 = *(const bf16x8*)(qb + (size_t)(q0 + qrow) * rs + (g << 3));
  const bf16x8 qf1 = *(const bf16x8*)(qb + (size_t)(q0 + qrow) * rs + 32 + (g << 3));

  const int tf = (blockIdx.x >= 4) ? 0 : (4 - (int)blockIdx.x);

  auto stage = [&](int bufi, int t) {
    const int j0 = q0 - 256 + t * 64;
    const int sl = (lane & 7) ^ ((lane >> 3) & 7);
#pragma unroll
    for (int j = 0; j < 2; ++j) {
      const int chunk = wid * 2 + j;
      const int row = chunk * 8 + (lane >> 3);
      gload_lds16(kb + (size_t)(j0 + row) * rs + sl * 8, &Ks[bufi][chunk * 512]);
      gload_lds16(vb + (size_t)row * 2048 + j0 + sl * 8, &Vs[bufi][chunk * 512]);
    }
  };

  f32x4 o[4] = {};
  float l_part[4] = {0.f, 0.f, 0.f, 0.f};

  stage(tf & 1, tf);
  for (int t = tf; t < 5; ++t) {
    __syncthreads();                        // tile-t writes visible to all waves
    if (t + 1 < 5) stage((t + 1) & 1, t + 1);

    const unsigned short* Kc = Ks[t & 1];
    const unsigned short* Vc = Vs[t & 1];

    f32x4 s[4];
#pragma unroll
    for (int ni = 0; ni < 4; ++ni) {
      const int kr = ni * 16 + li;
      const int sw = (kr & 7);
      bf16x8 kf0 = *(const bf16x8*)&Kc[kr * 64 + ((g ^ sw) << 3)];
      bf16x8 kf1 = *(const bf16x8*)&Kc[kr * 64 + (((4 + g) ^ sw) << 3)];
      f32x4 z = {};
      z = __builtin_amdgcn_mfma_f32_16x16x32_bf16(qf0, kf0, z, 0, 0, 0);
      z = __builtin_amdgcn_mfma_f32_16x16x32_bf16(qf1, kf1, z, 0, 0, 0);
      s[ni] = z;
    }
    const int rt = wid * 16 + g * 4;
#pragma unroll
    for (int ni = 0; ni < 4; ++ni) {
      int ct = ni * 16 + li;
#pragma unroll
      for (int reg = 0; reg < 4; ++reg) {
        float sv = s[ni][reg];
        if (t == 4 && ct > rt + reg) sv = -3e30f;   // causal
        if (t == 0 && ct < rt + reg) sv = -3e30f;   // window lower bound
        s[ni][reg] = sv;
      }
    }
    // static-max softmax: P = exp2(s' - 16); masked -> 0
#pragma unroll
    for (int reg = 0; reg < 4; ++reg) {
      float ps = 0.f;
#pragma unroll
      for (int ni = 0; ni < 4; ++ni) {
        float p = __builtin_exp2f(s[ni][reg] - 16.0f);
        ps += p;
        Ps[(wid * 16 + g * 4 + reg) * 88 + ni * 16 + li] = f2bf(p);
      }
      l_part[reg] += ps;
    }
    asm volatile("s_waitcnt lgkmcnt(0)" ::: "memory");
    __builtin_amdgcn_sched_barrier(0);
    const bf16x8 pf0 = *(const bf16x8*)&Ps[(wid * 16 + li) * 88 + (g << 3)];
    const bf16x8 pf1 = *(const bf16x8*)&Ps[(wid * 16 + li) * 88 + 32 + (g << 3)];
#pragma unroll
    for (int ni = 0; ni < 4; ++ni) {
      const int dr = ni * 16 + li;
      const int sw = (dr & 7);
      bf16x8 vf0 = *(const bf16x8*)&Vc[dr * 64 + ((g ^ sw) << 3)];
      bf16x8 vf1 = *(const bf16x8*)&Vc[dr * 64 + (((4 + g) ^ sw) << 3)];
      o[ni] = __builtin_amdgcn_mfma_f32_16x16x32_bf16(pf0, vf0, o[ni], 0, 0, 0);
      o[ni] = __builtin_amdgcn_mfma_f32_16x16x32_bf16(pf1, vf1, o[ni], 0, 0, 0);
    }
  }

  float inv[4];
#pragma unroll
  for (int reg = 0; reg < 4; ++reg) {
    float L = l_part[reg];
    L += __shfl_xor(L, 1, 64);
    L += __shfl_xor(L, 2, 64);
    L += __shfl_xor(L, 4, 64);
    L += __shfl_xor(L, 8, 64);
    inv[reg] = 1.f / L;
  }
#pragma unroll
  for (int ni = 0; ni < 4; ++ni) {
#pragma unroll
    for (int reg = 0; reg < 4; ++reg) {
      size_t row = (size_t)b * 2048 + q0 + wid * 16 + g * 4 + reg;
      attn[row * 1024 + h * 64 + ni * 16 + li] = f2bf(o[ni][reg] * inv[reg]);
    }
  }
}

// ---------------------------------------------------------------------------
extern "C" void kernel_launch(void* const* d_in, const int* in_sizes, int n_in,
                              void* d_out, int out_size, void* d_ws, size_t ws_size,
                              hipStream_t stream) {
  const float* x    = (const float*)d_in[0];   // (4096, 1024)
  const float* Wqkv = (const float*)d_in[1];   // (1024, 3072)
  const float* bqkv = (const float*)d_in[2];   // (3072)
  const float* Wout = (const float*)d_in[3];   // (1024, 1024)
  const float* bout = (const float*)d_in[4];   // (1024)
  float* out = (float*)d_out;                  // (4096, 1024)

  uint8_t* ws = (uint8_t*)d_ws;
  unsigned short* xb    = (unsigned short*)(ws);              //  8.0 MB x bf16
  unsigned short* wqT   = (unsigned short*)(ws +  8388608);   //  6.0 MB Wqkv^T
  unsigned short* woT   = (unsigned short*)(ws + 14680064);   //  2.0 MB Wout^T
  unsigned short* qkvb  = (unsigned short*)(ws + 16777216);   // 24.0 MB qkv
  unsigned short* attnb = (unsigned short*)(ws + 41943040);   //  8.0 MB attn out
  unsigned short* vTb   = (unsigned short*)(ws + 50331648);   //  8.0 MB V^T
  float*          bqs   = (float*)(ws + 58720256);            // 12 KB scaled bias

  k_prep<<<8204, 256, 0, stream>>>(x, Wqkv, Wout, bqkv, xb, wqT, woT, bqs);
  k_gemm32<<<dim3(3072 / 192, 4096 / 128), 256, 0, stream>>>(
      xb, wqT, bqs, qkvb, vTb, 4096, 3072, 1024);
  k_attn3<<<dim3(2048 / 64, 32), 256, 0, stream>>>(qkvb, vTb, attnb);
  k_gemm<64, 64, true, false><<<dim3(1024 / 64, 4096 / 128), 256, 0, stream>>>(
      attnb, woT, bout, out, nullptr, 4096, 1024, 1024);
}

// Round 16
// 89.932 us; speedup vs baseline: 1.0219x; 1.0219x over previous
//
#include <hip/hip_runtime.h>
#include <stdint.h>

// ---------------------------------------------------------------------------
// WindowedAttn: x(2,2048,1024) f32 -> QKV proj -> windowed causal attn (W=256)
// -> out proj. bf16 MFMA pipeline, f32 in/out.
// Round 16: champion restore (= r13, measured 89.46us). gemm = BK=64 dbuf
// single-barrier (BN=192 qkv / BN=64 out-proj), fused V^T epilogue, merged
// prep with Q-scale folding, attn = 64-row tiles + static-max exp2 softmax.
// All axes bracketed: schedules x4, BN{128,192,256}, BK{32,64}, MFMA shape
// {16x16,32x32}, prefetch depth{1,2}, attn QBLK{64,128}, softmax{online,
// static}. This config is the measured optimum of the family.
// ---------------------------------------------------------------------------

typedef __attribute__((ext_vector_type(8))) short bf16x8;     // 8 bf16 (4 VGPR)
typedef __attribute__((ext_vector_type(4))) float f32x4;      // MFMA C/D
typedef __attribute__((ext_vector_type(4))) unsigned int u32x4;
typedef __attribute__((ext_vector_type(4))) unsigned short u16x4;

#define DEV static __device__ __forceinline__

#define SC2 0.18033688011112042f   // 0.125 * log2(e), folded into Wq + bq

DEV unsigned short f2bf(float f) {            // f32 -> bf16 RNE
  unsigned int u = __builtin_bit_cast(unsigned int, f);
  u += 0x7fffu + ((u >> 16) & 1u);
  return (unsigned short)(u >> 16);
}

DEV void gload_lds16(const void* g, void* l) { // 16B global -> LDS direct
  __builtin_amdgcn_global_load_lds((const __attribute__((address_space(1))) void*)g,
                                   (__attribute__((address_space(3))) void*)l,
                                   16, 0, 0);
}

// ------------- prep: x->bf16, Wqkv^T (Q cols pre-scaled), Wout^T, bias -----
__global__ __launch_bounds__(256) void k_prep(const float* __restrict__ x,
                                              const float* __restrict__ Wqkv,
                                              const float* __restrict__ Wout,
                                              const float* __restrict__ bqkv,
                                              unsigned short* __restrict__ xb,
                                              unsigned short* __restrict__ wqT,
                                              unsigned short* __restrict__ woT,
                                              float* __restrict__ bqkv_s) {
  __shared__ float t[32][33];
  const int bid = blockIdx.x, tid = threadIdx.x;
  if (bid < 4096) {
    int i = bid * 256 + tid;
    f32x4 v = ((const f32x4*)x)[i];
    u16x4 o;
    o[0] = f2bf(v[0]); o[1] = f2bf(v[1]); o[2] = f2bf(v[2]); o[3] = f2bf(v[3]);
    ((u16x4*)xb)[i] = o;
    return;
  }
  if (bid >= 8192) {                        // scaled bias (bq *= SC2)
    int i = (bid - 8192) * 256 + tid;
    if (i < 3072) bqkv_s[i] = bqkv[i] * (i < 1024 ? SC2 : 1.0f);
    return;
  }
  const float* in;
  unsigned short* out;
  int N, K, n0, k0;
  float wscale = 1.0f;
  if (bid < 7168) {                         // Wqkv: (1024,3072) -> (3072,1024)
    int tt = bid - 4096;
    in = Wqkv; out = wqT; N = 3072; K = 1024;
    n0 = (tt % 96) * 32; k0 = (tt / 96) * 32;
    if (n0 < 1024) wscale = SC2;            // Q columns pre-scaled
  } else {                                  // Wout: (1024,1024) -> (1024,1024)
    int tt = bid - 7168;
    in = Wout; out = woT; N = 1024; K = 1024;
    n0 = (tt % 32) * 32; k0 = (tt / 32) * 32;
  }
  const int tx = tid & 31, ty = tid >> 5;   // 32 x 8
#pragma unroll
  for (int i = 0; i < 4; ++i)
    t[ty + i * 8][tx] = in[(size_t)(k0 + ty + i * 8) * N + n0 + tx];
  __syncthreads();
#pragma unroll
  for (int i = 0; i < 4; ++i)
    out[(size_t)(n0 + ty + i * 8) * K + k0 + tx] = f2bf(t[tx][ty + i * 8] * wscale);
}

// -------- bf16 GEMM: BK=64, 128 x BN tile, 2-buf single-barrier ------------
// C[M][N] = A[M][K] @ Bt[N][K]^T + bias. 4 waves (2x2); wave tile 64 x BN/2.
// Per iter: ONE __syncthreads (own vmcnt drained pre-barrier -> cross-wave
// staging safe) -> stage(kt+1 -> buf^1) -> 2 k-halves of frag ds_reads+MFMA.
// Swizzle: physical slot p holds logical p ^ (row&7); frag read of logical L
// reads physical L ^ (r&7) -> conflict-free (measured 0 conflicts).
// FUSE_VT: cols >= 2048 (V third of qkv) also written transposed.
template <int BN, bool F32OUT, bool FUSE_VT>
__global__ __launch_bounds__(256) void k_gemm(const unsigned short* __restrict__ A,
                                              const unsigned short* __restrict__ Bt,
                                              const float* __restrict__ bias,
                                              void* __restrict__ Cout,
                                              unsigned short* __restrict__ vT,
                                              int M, int N, int K) {
  constexpr int NI = BN / 32;               // B frags per wave
  constexpr int NCH = 16 + BN / 8;          // 8-row staging chunks (A then B)
  __shared__ unsigned short As[2][128 * 64];
  __shared__ unsigned short Bs[2][BN * 64];
  const int tid = threadIdx.x;
  const int lane = tid & 63, wid = tid >> 6;
  const int wr = wid >> 1, wc = wid & 1;
  const int g = lane >> 4, li = lane & 15;
  const int m0 = blockIdx.y * 128, n0 = blockIdx.x * BN;

  f32x4 acc[4][NI] = {};

  const int nkt = K >> 6;                   // BK=64 iterations
  const int r8 = lane >> 3, sp = lane & 7;

  auto stage = [&](int bufi, int kt) {
#pragma unroll
    for (int c = wid; c < NCH; c += 4) {
      if (c < 16) {
        int row = c * 8 + r8;
        int sl = sp ^ (row & 7);
        gload_lds16(A + (size_t)(m0 + row) * K + kt * 64 + sl * 8,
                    &As[bufi][c * 512]);
      } else {
        int cc = c - 16;
        int row = cc * 8 + r8;
        int sl = sp ^ (row & 7);
        gload_lds16(Bt + (size_t)(n0 + row) * K + kt * 64 + sl * 8,
                    &Bs[bufi][cc * 512]);
      }
    }
  };

  stage(0, 0);
  for (int kt = 0; kt < nkt; ++kt) {
    __syncthreads();                        // tile-kt landed; buf^1 reads retired
    if (kt + 1 < nkt) stage((kt + 1) & 1, kt + 1);   // prefetch under compute
    const unsigned short* Ac = As[kt & 1];
    const unsigned short* Bc = Bs[kt & 1];
#pragma unroll
    for (int h = 0; h < 2; ++h) {           // two k-halves of 32
      bf16x8 af[4], bfr[NI];
#pragma unroll
      for (int mi = 0; mi < 4; ++mi) {
        const int r = wr * 64 + mi * 16 + li;
        const int slot = (g + h * 4) ^ (r & 7);
        af[mi] = *(const bf16x8*)&Ac[r * 64 + slot * 8];
      }
#pragma unroll
      for (int ni = 0; ni < NI; ++ni) {
        const int r = wc * (BN / 2) + ni * 16 + li;
        const int slot = (g + h * 4) ^ (r & 7);
        bfr[ni] = *(const bf16x8*)&Bc[r * 64 + slot * 8];
      }
#pragma unroll
      for (int mi = 0; mi < 4; ++mi)
#pragma unroll
        for (int ni = 0; ni < NI; ++ni)
          acc[mi][ni] = __builtin_amdgcn_mfma_f32_16x16x32_bf16(af[mi], bfr[ni],
                                                                acc[mi][ni], 0, 0, 0);
    }
  }

  // epilogue: C/D layout col = li, row = g*4 + reg
  float bv[NI];
#pragma unroll
  for (int ni = 0; ni < NI; ++ni) bv[ni] = bias[n0 + wc * (BN / 2) + ni * 16 + li];
#pragma unroll
  for (int mi = 0; mi < 4; ++mi) {
#pragma unroll
    for (int ni = 0; ni < NI; ++ni) {
      const int col = n0 + wc * (BN / 2) + ni * 16 + li;
      const int row0 = m0 + wr * 64 + mi * 16 + g * 4;
      float v0 = acc[mi][ni][0] + bv[ni];
      float v1 = acc[mi][ni][1] + bv[ni];
      float v2 = acc[mi][ni][2] + bv[ni];
      float v3 = acc[mi][ni][3] + bv[ni];
      if (F32OUT) {
        float* C = (float*)Cout;
        C[(size_t)(row0 + 0) * N + col] = v0;
        C[(size_t)(row0 + 1) * N + col] = v1;
        C[(size_t)(row0 + 2) * N + col] = v2;
        C[(size_t)(row0 + 3) * N + col] = v3;
      } else {
        unsigned short* C = (unsigned short*)Cout;
        C[(size_t)(row0 + 0) * N + col] = f2bf(v0);
        C[(size_t)(row0 + 1) * N + col] = f2bf(v1);
        C[(size_t)(row0 + 2) * N + col] = f2bf(v2);
        C[(size_t)(row0 + 3) * N + col] = f2bf(v3);
      }
      if (FUSE_VT && col >= 2048) {         // V third: also write transposed
        const int b = row0 >> 11;
        const int s = row0 & 2047;
        u16x4 vv;
        vv[0] = f2bf(v0); vv[1] = f2bf(v1); vv[2] = f2bf(v2); vv[3] = f2bf(v3);
        *(u16x4*)&vT[(size_t)(b * 1024 + col - 2048) * 2048 + s] = vv;
      }
    }
  }
}

// ---------- windowed flash attention (static-max softmax, exp2) ------------
// qkv: (4096,3072) bf16 = [Q(pre-scaled by SC2)|K|V]; vT per (b,h): 64 d-rows
// x 2048 keys. Block = (b,h,q-tile 64), 4 waves x 16 q-rows. K and V^T staged
// via global_load_lds (linear dest, XOR slot pre-swizzle both sides), dbuf
// with counted vmcnt(4) (own-vmcnt BEFORE the shared barrier -> safe).
// Softmax: P = exp2(s' - 16), no running max (|s'|<~6; constant divides out).
__global__ __launch_bounds__(256) void k_attn3(const unsigned short* __restrict__ qkv,
                                               const unsigned short* __restrict__ vT,
                                               unsigned short* __restrict__ attn) {
  __shared__ unsigned short Ks[2][64 * 64];
  __shared__ unsigned short Vs[2][64 * 64];
  __shared__ unsigned short Ps[64 * 88];
  const int tid = threadIdx.x, lane = tid & 63, wid = tid >> 6;
  const int g = lane >> 4, li = lane & 15;
  const int bh = blockIdx.y, b = bh >> 4, h = bh & 15;
  const int q0 = blockIdx.x * 64;
  const size_t rs = 3072;
  const unsigned short* qb = qkv + (size_t)b * 2048 * rs + h * 64;
  const unsigned short* kb = qb + 1024;
  const unsigned short* vb = vT + (size_t)bh * 64 * 2048;

  const int qrow = wid * 16 + li;
  const bf16x8 qf0 = *(const bf16x8*)(qb + (size_t)(q0 + qrow) * rs + (g << 3));
  const bf16x8 qf1 = *(const bf16x8*)(qb + (size_t)(q0 + qrow) * rs + 32 + (g << 3));

  const int tf = (blockIdx.x >= 4) ? 0 : (4 - (int)blockIdx.x);

  auto stage = [&](int bufi, int t) {
    const int j0 = q0 - 256 + t * 64;
    const int sl = (lane & 7) ^ ((lane >> 3) & 7);
#pragma unroll
    for (int j = 0; j < 2; ++j) {
      const int chunk = wid * 2 + j;
      const int row = chunk * 8 + (lane >> 3);
      gload_lds16(kb + (size_t)(j0 + row) * rs + sl * 8, &Ks[bufi][chunk * 512]);
      gload_lds16(vb + (size_t)row * 2048 + j0 + sl * 8, &Vs[bufi][chunk * 512]);
    }
  };

  f32x4 o[4] = {};
  float l_part[4] = {0.f, 0.f, 0.f, 0.f};

  stage(0, tf);
  int cur = 0;
  for (int t = tf; t < 5; ++t) {
    if (t + 1 < 5) {
      stage(cur ^ 1, t + 1);
      asm volatile("s_waitcnt vmcnt(4)" ::: "memory");
    } else {
      asm volatile("s_waitcnt vmcnt(0)" ::: "memory");
    }
    __builtin_amdgcn_sched_barrier(0);
    __builtin_amdgcn_s_barrier();
    __builtin_amdgcn_sched_barrier(0);

    const unsigned short* Kc = Ks[cur];
    const unsigned short* Vc = Vs[cur];

    f32x4 s[4];
#pragma unroll
    for (int ni = 0; ni < 4; ++ni) {
      const int kr = ni * 16 + li;
      const int sw = (kr & 7);
      bf16x8 kf0 = *(const bf16x8*)&Kc[kr * 64 + ((g ^ sw) << 3)];
      bf16x8 kf1 = *(const bf16x8*)&Kc[kr * 64 + (((4 + g) ^ sw) << 3)];
      f32x4 z = {};
      z = __builtin_amdgcn_mfma_f32_16x16x32_bf16(qf0, kf0, z, 0, 0, 0);
      z = __builtin_amdgcn_mfma_f32_16x16x32_bf16(qf1, kf1, z, 0, 0, 0);
      s[ni] = z;
    }
    const int rt = wid * 16 + g * 4;
#pragma unroll
    for (int ni = 0; ni < 4; ++ni) {
      int ct = ni * 16 + li;
#pragma unroll
      for (int reg = 0; reg < 4; ++reg) {
        float sv = s[ni][reg];
        if (t == 4 && ct > rt + reg) sv = -3e30f;   // causal
        if (t == 0 && ct < rt + reg) sv = -3e30f;   // window lower bound
        s[ni][reg] = sv;
      }
    }
    // static-max softmax: P = exp2(s' - 16); masked -> 0
#pragma unroll
    for (int reg = 0; reg < 4; ++reg) {
      float ps = 0.f;
#pragma unroll
      for (int ni = 0; ni < 4; ++ni) {
        float p = __builtin_exp2f(s[ni][reg] - 16.0f);
        ps += p;
        Ps[(wid * 16 + g * 4 + reg) * 88 + ni * 16 + li] = f2bf(p);
      }
      l_part[reg] += ps;
    }
    // wave-private P round-trip (rule 18: explicit wait + sched fence)
    asm volatile("s_waitcnt lgkmcnt(0)" ::: "memory");
    __builtin_amdgcn_sched_barrier(0);
    const bf16x8 pf0 = *(const bf16x8*)&Ps[(wid * 16 + li) * 88 + (g << 3)];
    const bf16x8 pf1 = *(const bf16x8*)&Ps[(wid * 16 + li) * 88 + 32 + (g << 3)];
#pragma unroll
    for (int ni = 0; ni < 4; ++ni) {
      const int dr = ni * 16 + li;
      const int sw = (dr & 7);
      bf16x8 vf0 = *(const bf16x8*)&Vc[dr * 64 + ((g ^ sw) << 3)];
      bf16x8 vf1 = *(const bf16x8*)&Vc[dr * 64 + (((4 + g) ^ sw) << 3)];
      o[ni] = __builtin_amdgcn_mfma_f32_16x16x32_bf16(pf0, vf0, o[ni], 0, 0, 0);
      o[ni] = __builtin_amdgcn_mfma_f32_16x16x32_bf16(pf1, vf1, o[ni], 0, 0, 0);
    }
    __builtin_amdgcn_sched_barrier(0);
    __builtin_amdgcn_s_barrier();
    cur ^= 1;
  }

  float inv[4];
#pragma unroll
  for (int reg = 0; reg < 4; ++reg) {
    float L = l_part[reg];
    L += __shfl_xor(L, 1, 64);
    L += __shfl_xor(L, 2, 64);
    L += __shfl_xor(L, 4, 64);
    L += __shfl_xor(L, 8, 64);
    inv[reg] = 1.f / L;
  }
#pragma unroll
  for (int ni = 0; ni < 4; ++ni) {
#pragma unroll
    for (int reg = 0; reg < 4; ++reg) {
      size_t row = (size_t)b * 2048 + q0 + wid * 16 + g * 4 + reg;
      attn[row * 1024 + h * 64 + ni * 16 + li] = f2bf(o[ni][reg] * inv[reg]);
    }
  }
}

// ---------------------------------------------------------------------------
extern "C" void kernel_launch(void* const* d_in, const int* in_sizes, int n_in,
                              void* d_out, int out_size, void* d_ws, size_t ws_size,
                              hipStream_t stream) {
  const float* x    = (const float*)d_in[0];   // (4096, 1024)
  const float* Wqkv = (const float*)d_in[1];   // (1024, 3072)
  const float* bqkv = (const float*)d_in[2];   // (3072)
  const float* Wout = (const float*)d_in[3];   // (1024, 1024)
  const float* bout = (const float*)d_in[4];   // (1024)
  float* out = (float*)d_out;                  // (4096, 1024)

  uint8_t* ws = (uint8_t*)d_ws;
  unsigned short* xb    = (unsigned short*)(ws);              //  8.0 MB x bf16
  unsigned short* wqT   = (unsigned short*)(ws +  8388608);   //  6.0 MB Wqkv^T
  unsigned short* woT   = (unsigned short*)(ws + 14680064);   //  2.0 MB Wout^T
  unsigned short* qkvb  = (unsigned short*)(ws + 16777216);   // 24.0 MB qkv
  unsigned short* attnb = (unsigned short*)(ws + 41943040);   //  8.0 MB attn out
  unsigned short* vTb   = (unsigned short*)(ws + 50331648);   //  8.0 MB V^T
  float*          bqs   = (float*)(ws + 58720256);            // 12 KB scaled bias

  k_prep<<<8204, 256, 0, stream>>>(x, Wqkv, Wout, bqkv, xb, wqT, woT, bqs);
  k_gemm<192, false, true><<<dim3(3072 / 192, 4096 / 128), 256, 0, stream>>>(
      xb, wqT, bqs, qkvb, vTb, 4096, 3072, 1024);
  k_attn3<<<dim3(2048 / 64, 32), 256, 0, stream>>>(qkvb, vTb, attnb);
  k_gemm<64, true, false><<<dim3(1024 / 64, 4096 / 128), 256, 0, stream>>>(
      attnb, woT, bout, out, nullptr, 4096, 1024, 1024);
}

// Round 17
// 86.606 us; speedup vs baseline: 1.0611x; 1.0384x over previous
//
#include <hip/hip_runtime.h>
#include <stdint.h>

// ---------------------------------------------------------------------------
// WindowedAttn: x(2,2048,1024) f32 -> QKV proj -> windowed causal attn (W=256)
// -> out proj. bf16 MFMA pipeline, f32 in/out.
// Round 17: gemm1 = 256x192 tile, 8 waves (512 thr), BK=64 dbuf 1-barrier
// (block-iters/CU halved: 512x16@2/CU -> 256x16@1/CU, grid = exactly 256).
// gemm2 <128-tile,64>, attn static-max, prep unchanged (r16 champion).
// ---------------------------------------------------------------------------

typedef __attribute__((ext_vector_type(8))) short bf16x8;     // 8 bf16 (4 VGPR)
typedef __attribute__((ext_vector_type(4))) float f32x4;      // MFMA C/D
typedef __attribute__((ext_vector_type(4))) unsigned int u32x4;
typedef __attribute__((ext_vector_type(4))) unsigned short u16x4;

#define DEV static __device__ __forceinline__

#define SC2 0.18033688011112042f   // 0.125 * log2(e), folded into Wq + bq

DEV unsigned short f2bf(float f) {            // f32 -> bf16 RNE
  unsigned int u = __builtin_bit_cast(unsigned int, f);
  u += 0x7fffu + ((u >> 16) & 1u);
  return (unsigned short)(u >> 16);
}

DEV void gload_lds16(const void* g, void* l) { // 16B global -> LDS direct
  __builtin_amdgcn_global_load_lds((const __attribute__((address_space(1))) void*)g,
                                   (__attribute__((address_space(3))) void*)l,
                                   16, 0, 0);
}

// ------------- prep: x->bf16, Wqkv^T (Q cols pre-scaled), Wout^T, bias -----
__global__ __launch_bounds__(256) void k_prep(const float* __restrict__ x,
                                              const float* __restrict__ Wqkv,
                                              const float* __restrict__ Wout,
                                              const float* __restrict__ bqkv,
                                              unsigned short* __restrict__ xb,
                                              unsigned short* __restrict__ wqT,
                                              unsigned short* __restrict__ woT,
                                              float* __restrict__ bqkv_s) {
  __shared__ float t[32][33];
  const int bid = blockIdx.x, tid = threadIdx.x;
  if (bid < 4096) {
    int i = bid * 256 + tid;
    f32x4 v = ((const f32x4*)x)[i];
    u16x4 o;
    o[0] = f2bf(v[0]); o[1] = f2bf(v[1]); o[2] = f2bf(v[2]); o[3] = f2bf(v[3]);
    ((u16x4*)xb)[i] = o;
    return;
  }
  if (bid >= 8192) {                        // scaled bias (bq *= SC2)
    int i = (bid - 8192) * 256 + tid;
    if (i < 3072) bqkv_s[i] = bqkv[i] * (i < 1024 ? SC2 : 1.0f);
    return;
  }
  const float* in;
  unsigned short* out;
  int N, K, n0, k0;
  float wscale = 1.0f;
  if (bid < 7168) {                         // Wqkv: (1024,3072) -> (3072,1024)
    int tt = bid - 4096;
    in = Wqkv; out = wqT; N = 3072; K = 1024;
    n0 = (tt % 96) * 32; k0 = (tt / 96) * 32;
    if (n0 < 1024) wscale = SC2;            // Q columns pre-scaled
  } else {                                  // Wout: (1024,1024) -> (1024,1024)
    int tt = bid - 7168;
    in = Wout; out = woT; N = 1024; K = 1024;
    n0 = (tt % 32) * 32; k0 = (tt / 32) * 32;
  }
  const int tx = tid & 31, ty = tid >> 5;   // 32 x 8
#pragma unroll
  for (int i = 0; i < 4; ++i)
    t[ty + i * 8][tx] = in[(size_t)(k0 + ty + i * 8) * N + n0 + tx];
  __syncthreads();
#pragma unroll
  for (int i = 0; i < 4; ++i)
    out[(size_t)(n0 + ty + i * 8) * K + k0 + tx] = f2bf(t[tx][ty + i * 8] * wscale);
}

// -------- gemm1: 256x192 tile, 8 waves, BK=64, 2-buf single-barrier --------
// C = A @ Bt^T + bias (bf16 out) + fused V^T write. Waves 4(M) x 2(N); wave
// tile 64x96 (identical per-wave work/VGPR to the r16 champion). Grid 16x16 =
// 256 blocks = exactly 1/CU, 8 waves/CU. Dynamic LDS 112KB (2 bufs of
// A[256][64] + B[192][64]). Same XOR swizzle (slot ^= row&7) -> conflict-free.
__global__ __launch_bounds__(512) void k_gemm1big(const unsigned short* __restrict__ A,
                                                  const unsigned short* __restrict__ Bt,
                                                  const float* __restrict__ bias,
                                                  unsigned short* __restrict__ C,
                                                  unsigned short* __restrict__ vT,
                                                  int M, int N, int K) {
  extern __shared__ unsigned short lds[];
  // layout: As0[16384] As1[16384] Bs0[12288] Bs1[12288]  (ushorts)
  const int tid = threadIdx.x;
  const int lane = tid & 63, wid = tid >> 6;     // 8 waves
  const int wr = wid >> 1, wc = wid & 1;         // 4(M) x 2(N)
  const int g = lane >> 4, li = lane & 15;
  const int m0 = blockIdx.y * 256, n0 = blockIdx.x * 192;

  f32x4 acc[4][6] = {};
  const int nkt = K >> 6;                   // BK=64
  const int r8 = lane >> 3, sp = lane & 7;

  auto Abuf = [&](int i) { return lds + i * 16384; };
  auto Bbuf = [&](int i) { return lds + 32768 + i * 12288; };

  auto stage = [&](int bufi, int kt) {
#pragma unroll
    for (int c = wid; c < 56; c += 8) {     // 32 A-chunks + 24 B-chunks of 8 rows
      if (c < 32) {
        int row = c * 8 + r8;
        int sl = sp ^ (row & 7);
        gload_lds16(A + (size_t)(m0 + row) * K + kt * 64 + sl * 8,
                    Abuf(bufi) + c * 512);
      } else {
        int cc = c - 32;
        int row = cc * 8 + r8;
        int sl = sp ^ (row & 7);
        gload_lds16(Bt + (size_t)(n0 + row) * K + kt * 64 + sl * 8,
                    Bbuf(bufi) + cc * 512);
      }
    }
  };

  stage(0, 0);
  for (int kt = 0; kt < nkt; ++kt) {
    __syncthreads();                        // tile-kt landed; buf^1 reads retired
    if (kt + 1 < nkt) stage((kt + 1) & 1, kt + 1);   // prefetch under compute
    const unsigned short* Ac = Abuf(kt & 1);
    const unsigned short* Bc = Bbuf(kt & 1);
#pragma unroll
    for (int h = 0; h < 2; ++h) {           // two k-halves of 32
      bf16x8 af[4], bfr[6];
#pragma unroll
      for (int mi = 0; mi < 4; ++mi) {
        const int r = wr * 64 + mi * 16 + li;
        const int slot = (g + h * 4) ^ (r & 7);
        af[mi] = *(const bf16x8*)&Ac[r * 64 + slot * 8];
      }
#pragma unroll
      for (int ni = 0; ni < 6; ++ni) {
        const int r = wc * 96 + ni * 16 + li;
        const int slot = (g + h * 4) ^ (r & 7);
        bfr[ni] = *(const bf16x8*)&Bc[r * 64 + slot * 8];
      }
#pragma unroll
      for (int mi = 0; mi < 4; ++mi)
#pragma unroll
        for (int ni = 0; ni < 6; ++ni)
          acc[mi][ni] = __builtin_amdgcn_mfma_f32_16x16x32_bf16(af[mi], bfr[ni],
                                                                acc[mi][ni], 0, 0, 0);
    }
  }

  // epilogue: C/D layout col = li, row = g*4 + reg
  float bv[6];
#pragma unroll
  for (int ni = 0; ni < 6; ++ni) bv[ni] = bias[n0 + wc * 96 + ni * 16 + li];
#pragma unroll
  for (int mi = 0; mi < 4; ++mi) {
#pragma unroll
    for (int ni = 0; ni < 6; ++ni) {
      const int col = n0 + wc * 96 + ni * 16 + li;
      const int row0 = m0 + wr * 64 + mi * 16 + g * 4;
      float v0 = acc[mi][ni][0] + bv[ni];
      float v1 = acc[mi][ni][1] + bv[ni];
      float v2 = acc[mi][ni][2] + bv[ni];
      float v3 = acc[mi][ni][3] + bv[ni];
      C[(size_t)(row0 + 0) * N + col] = f2bf(v0);
      C[(size_t)(row0 + 1) * N + col] = f2bf(v1);
      C[(size_t)(row0 + 2) * N + col] = f2bf(v2);
      C[(size_t)(row0 + 3) * N + col] = f2bf(v3);
      if (col >= 2048) {                    // V third: also write transposed
        const int b = row0 >> 11;
        const int s = row0 & 2047;
        u16x4 vv;
        vv[0] = f2bf(v0); vv[1] = f2bf(v1); vv[2] = f2bf(v2); vv[3] = f2bf(v3);
        *(u16x4*)&vT[(size_t)(b * 1024 + col - 2048) * 2048 + s] = vv;
      }
    }
  }
}

// -------- bf16 GEMM: BK=64, 128 x BN tile, 4 waves, 2-buf (out-proj) -------
template <int BN, bool F32OUT>
__global__ __launch_bounds__(256) void k_gemm(const unsigned short* __restrict__ A,
                                              const unsigned short* __restrict__ Bt,
                                              const float* __restrict__ bias,
                                              void* __restrict__ Cout,
                                              int M, int N, int K) {
  constexpr int NI = BN / 32;
  constexpr int NCH = 16 + BN / 8;
  __shared__ unsigned short As[2][128 * 64];
  __shared__ unsigned short Bs[2][BN * 64];
  const int tid = threadIdx.x;
  const int lane = tid & 63, wid = tid >> 6;
  const int wr = wid >> 1, wc = wid & 1;
  const int g = lane >> 4, li = lane & 15;
  const int m0 = blockIdx.y * 128, n0 = blockIdx.x * BN;

  f32x4 acc[4][NI] = {};
  const int nkt = K >> 6;
  const int r8 = lane >> 3, sp = lane & 7;

  auto stage = [&](int bufi, int kt) {
#pragma unroll
    for (int c = wid; c < NCH; c += 4) {
      if (c < 16) {
        int row = c * 8 + r8;
        int sl = sp ^ (row & 7);
        gload_lds16(A + (size_t)(m0 + row) * K + kt * 64 + sl * 8,
                    &As[bufi][c * 512]);
      } else {
        int cc = c - 16;
        int row = cc * 8 + r8;
        int sl = sp ^ (row & 7);
        gload_lds16(Bt + (size_t)(n0 + row) * K + kt * 64 + sl * 8,
                    &Bs[bufi][cc * 512]);
      }
    }
  };

  stage(0, 0);
  for (int kt = 0; kt < nkt; ++kt) {
    __syncthreads();
    if (kt + 1 < nkt) stage((kt + 1) & 1, kt + 1);
    const unsigned short* Ac = As[kt & 1];
    const unsigned short* Bc = Bs[kt & 1];
#pragma unroll
    for (int h = 0; h < 2; ++h) {
      bf16x8 af[4], bfr[NI];
#pragma unroll
      for (int mi = 0; mi < 4; ++mi) {
        const int r = wr * 64 + mi * 16 + li;
        const int slot = (g + h * 4) ^ (r & 7);
        af[mi] = *(const bf16x8*)&Ac[r * 64 + slot * 8];
      }
#pragma unroll
      for (int ni = 0; ni < NI; ++ni) {
        const int r = wc * (BN / 2) + ni * 16 + li;
        const int slot = (g + h * 4) ^ (r & 7);
        bfr[ni] = *(const bf16x8*)&Bc[r * 64 + slot * 8];
      }
#pragma unroll
      for (int mi = 0; mi < 4; ++mi)
#pragma unroll
        for (int ni = 0; ni < NI; ++ni)
          acc[mi][ni] = __builtin_amdgcn_mfma_f32_16x16x32_bf16(af[mi], bfr[ni],
                                                                acc[mi][ni], 0, 0, 0);
    }
  }

  float bv[NI];
#pragma unroll
  for (int ni = 0; ni < NI; ++ni) bv[ni] = bias[n0 + wc * (BN / 2) + ni * 16 + li];
#pragma unroll
  for (int mi = 0; mi < 4; ++mi) {
#pragma unroll
    for (int ni = 0; ni < NI; ++ni) {
      const int col = n0 + wc * (BN / 2) + ni * 16 + li;
      const int row0 = m0 + wr * 64 + mi * 16 + g * 4;
#pragma unroll
      for (int reg = 0; reg < 4; ++reg) {
        float v = acc[mi][ni][reg] + bv[ni];
        if (F32OUT) ((float*)Cout)[(size_t)(row0 + reg) * N + col] = v;
        else ((unsigned short*)Cout)[(size_t)(row0 + reg) * N + col] = f2bf(v);
      }
    }
  }
}

// ---------- windowed flash attention (static-max softmax, exp2) ------------
__global__ __launch_bounds__(256) void k_attn3(const unsigned short* __restrict__ qkv,
                                               const unsigned short* __restrict__ vT,
                                               unsigned short* __restrict__ attn) {
  __shared__ unsigned short Ks[2][64 * 64];
  __shared__ unsigned short Vs[2][64 * 64];
  __shared__ unsigned short Ps[64 * 88];
  const int tid = threadIdx.x, lane = tid & 63, wid = tid >> 6;
  const int g = lane >> 4, li = lane & 15;
  const int bh = blockIdx.y, b = bh >> 4, h = bh & 15;
  const int q0 = blockIdx.x * 64;
  const size_t rs = 3072;
  const unsigned short* qb = qkv + (size_t)b * 2048 * rs + h * 64;
  const unsigned short* kb = qb + 1024;
  const unsigned short* vb = vT + (size_t)bh * 64 * 2048;

  const int qrow = wid * 16 + li;
  const bf16x8 qf0 = *(const bf16x8*)(qb + (size_t)(q0 + qrow) * rs + (g << 3));
  const bf16x8 qf1 = *(const bf16x8*)(qb + (size_t)(q0 + qrow) * rs + 32 + (g << 3));

  const int tf = (blockIdx.x >= 4) ? 0 : (4 - (int)blockIdx.x);

  auto stage = [&](int bufi, int t) {
    const int j0 = q0 - 256 + t * 64;
    const int sl = (lane & 7) ^ ((lane >> 3) & 7);
#pragma unroll
    for (int j = 0; j < 2; ++j) {
      const int chunk = wid * 2 + j;
      const int row = chunk * 8 + (lane >> 3);
      gload_lds16(kb + (size_t)(j0 + row) * rs + sl * 8, &Ks[bufi][chunk * 512]);
      gload_lds16(vb + (size_t)row * 2048 + j0 + sl * 8, &Vs[bufi][chunk * 512]);
    }
  };

  f32x4 o[4] = {};
  float l_part[4] = {0.f, 0.f, 0.f, 0.f};

  stage(0, tf);
  int cur = 0;
  for (int t = tf; t < 5; ++t) {
    if (t + 1 < 5) {
      stage(cur ^ 1, t + 1);
      asm volatile("s_waitcnt vmcnt(4)" ::: "memory");
    } else {
      asm volatile("s_waitcnt vmcnt(0)" ::: "memory");
    }
    __builtin_amdgcn_sched_barrier(0);
    __builtin_amdgcn_s_barrier();
    __builtin_amdgcn_sched_barrier(0);

    const unsigned short* Kc = Ks[cur];
    const unsigned short* Vc = Vs[cur];

    f32x4 s[4];
#pragma unroll
    for (int ni = 0; ni < 4; ++ni) {
      const int kr = ni * 16 + li;
      const int sw = (kr & 7);
      bf16x8 kf0 = *(const bf16x8*)&Kc[kr * 64 + ((g ^ sw) << 3)];
      bf16x8 kf1 = *(const bf16x8*)&Kc[kr * 64 + (((4 + g) ^ sw) << 3)];
      f32x4 z = {};
      z = __builtin_amdgcn_mfma_f32_16x16x32_bf16(qf0, kf0, z, 0, 0, 0);
      z = __builtin_amdgcn_mfma_f32_16x16x32_bf16(qf1, kf1, z, 0, 0, 0);
      s[ni] = z;
    }
    const int rt = wid * 16 + g * 4;
#pragma unroll
    for (int ni = 0; ni < 4; ++ni) {
      int ct = ni * 16 + li;
#pragma unroll
      for (int reg = 0; reg < 4; ++reg) {
        float sv = s[ni][reg];
        if (t == 4 && ct > rt + reg) sv = -3e30f;   // causal
        if (t == 0 && ct < rt + reg) sv = -3e30f;   // window lower bound
        s[ni][reg] = sv;
      }
    }
    // static-max softmax: P = exp2(s' - 16); masked -> 0
#pragma unroll
    for (int reg = 0; reg < 4; ++reg) {
      float ps = 0.f;
#pragma unroll
      for (int ni = 0; ni < 4; ++ni) {
        float p = __builtin_exp2f(s[ni][reg] - 16.0f);
        ps += p;
        Ps[(wid * 16 + g * 4 + reg) * 88 + ni * 16 + li] = f2bf(p);
      }
      l_part[reg] += ps;
    }
    asm volatile("s_waitcnt lgkmcnt(0)" ::: "memory");
    __builtin_amdgcn_sched_barrier(0);
    const bf16x8 pf0 = *(const bf16x8*)&Ps[(wid * 16 + li) * 88 + (g << 3)];
    const bf16x8 pf1 = *(const bf16x8*)&Ps[(wid * 16 + li) * 88 + 32 + (g << 3)];
#pragma unroll
    for (int ni = 0; ni < 4; ++ni) {
      const int dr = ni * 16 + li;
      const int sw = (dr & 7);
      bf16x8 vf0 = *(const bf16x8*)&Vc[dr * 64 + ((g ^ sw) << 3)];
      bf16x8 vf1 = *(const bf16x8*)&Vc[dr * 64 + (((4 + g) ^ sw) << 3)];
      o[ni] = __builtin_amdgcn_mfma_f32_16x16x32_bf16(pf0, vf0, o[ni], 0, 0, 0);
      o[ni] = __builtin_amdgcn_mfma_f32_16x16x32_bf16(pf1, vf1, o[ni], 0, 0, 0);
    }
    __builtin_amdgcn_sched_barrier(0);
    __builtin_amdgcn_s_barrier();
    cur ^= 1;
  }

  float inv[4];
#pragma unroll
  for (int reg = 0; reg < 4; ++reg) {
    float L = l_part[reg];
    L += __shfl_xor(L, 1, 64);
    L += __shfl_xor(L, 2, 64);
    L += __shfl_xor(L, 4, 64);
    L += __shfl_xor(L, 8, 64);
    inv[reg] = 1.f / L;
  }
#pragma unroll
  for (int ni = 0; ni < 4; ++ni) {
#pragma unroll
    for (int reg = 0; reg < 4; ++reg) {
      size_t row = (size_t)b * 2048 + q0 + wid * 16 + g * 4 + reg;
      attn[row * 1024 + h * 64 + ni * 16 + li] = f2bf(o[ni][reg] * inv[reg]);
    }
  }
}

// ---------------------------------------------------------------------------
extern "C" void kernel_launch(void* const* d_in, const int* in_sizes, int n_in,
                              void* d_out, int out_size, void* d_ws, size_t ws_size,
                              hipStream_t stream) {
  const float* x    = (const float*)d_in[0];   // (4096, 1024)
  const float* Wqkv = (const float*)d_in[1];   // (1024, 3072)
  const float* bqkv = (const float*)d_in[2];   // (3072)
  const float* Wout = (const float*)d_in[3];   // (1024, 1024)
  const float* bout = (const float*)d_in[4];   // (1024)
  float* out = (float*)d_out;                  // (4096, 1024)

  uint8_t* ws = (uint8_t*)d_ws;
  unsigned short* xb    = (unsigned short*)(ws);              //  8.0 MB x bf16
  unsigned short* wqT   = (unsigned short*)(ws +  8388608);   //  6.0 MB Wqkv^T
  unsigned short* woT   = (unsigned short*)(ws + 14680064);   //  2.0 MB Wout^T
  unsigned short* qkvb  = (unsigned short*)(ws + 16777216);   // 24.0 MB qkv
  unsigned short* attnb = (unsigned short*)(ws + 41943040);   //  8.0 MB attn out
  unsigned short* vTb   = (unsigned short*)(ws + 50331648);   //  8.0 MB V^T
  float*          bqs   = (float*)(ws + 58720256);            // 12 KB scaled bias

  hipFuncSetAttribute((const void*)k_gemm1big,
                      hipFuncAttributeMaxDynamicSharedMemorySize, 114688);

  k_prep<<<8204, 256, 0, stream>>>(x, Wqkv, Wout, bqkv, xb, wqT, woT, bqs);
  k_gemm1big<<<dim3(3072 / 192, 4096 / 256), 512, 114688, stream>>>(
      xb, wqT, bqs, qkvb, vTb, 4096, 3072, 1024);
  k_attn3<<<dim3(2048 / 64, 32), 256, 0, stream>>>(qkvb, vTb, attnb);
  k_gemm<64, true><<<dim3(1024 / 64, 4096 / 128), 256, 0, stream>>>(
      attnb, woT, bout, out, 4096, 1024, 1024);
}

// Round 18
// 85.731 us; speedup vs baseline: 1.0720x; 1.0102x over previous
//
#include <hip/hip_runtime.h>
#include <stdint.h>

// ---------------------------------------------------------------------------
// WindowedAttn: x(2,2048,1024) f32 -> QKV proj -> windowed causal attn (W=256)
// -> out proj. bf16 MFMA pipeline, f32 in/out.
// Round 18: gemm2 also moved to the 256-row 8-wave big-tile (256x64, grid
// 16x16 = 256 blocks = 1/CU, block-iters/CU halved — same lever that won r17
// for gemm1). gemm1big 256x192, attn static-max, prep unchanged.
// ---------------------------------------------------------------------------

typedef __attribute__((ext_vector_type(8))) short bf16x8;     // 8 bf16 (4 VGPR)
typedef __attribute__((ext_vector_type(4))) float f32x4;      // MFMA C/D
typedef __attribute__((ext_vector_type(4))) unsigned int u32x4;
typedef __attribute__((ext_vector_type(4))) unsigned short u16x4;

#define DEV static __device__ __forceinline__

#define SC2 0.18033688011112042f   // 0.125 * log2(e), folded into Wq + bq

DEV unsigned short f2bf(float f) {            // f32 -> bf16 RNE
  unsigned int u = __builtin_bit_cast(unsigned int, f);
  u += 0x7fffu + ((u >> 16) & 1u);
  return (unsigned short)(u >> 16);
}

DEV void gload_lds16(const void* g, void* l) { // 16B global -> LDS direct
  __builtin_amdgcn_global_load_lds((const __attribute__((address_space(1))) void*)g,
                                   (__attribute__((address_space(3))) void*)l,
                                   16, 0, 0);
}

// ------------- prep: x->bf16, Wqkv^T (Q cols pre-scaled), Wout^T, bias -----
__global__ __launch_bounds__(256) void k_prep(const float* __restrict__ x,
                                              const float* __restrict__ Wqkv,
                                              const float* __restrict__ Wout,
                                              const float* __restrict__ bqkv,
                                              unsigned short* __restrict__ xb,
                                              unsigned short* __restrict__ wqT,
                                              unsigned short* __restrict__ woT,
                                              float* __restrict__ bqkv_s) {
  __shared__ float t[32][33];
  const int bid = blockIdx.x, tid = threadIdx.x;
  if (bid < 4096) {
    int i = bid * 256 + tid;
    f32x4 v = ((const f32x4*)x)[i];
    u16x4 o;
    o[0] = f2bf(v[0]); o[1] = f2bf(v[1]); o[2] = f2bf(v[2]); o[3] = f2bf(v[3]);
    ((u16x4*)xb)[i] = o;
    return;
  }
  if (bid >= 8192) {                        // scaled bias (bq *= SC2)
    int i = (bid - 8192) * 256 + tid;
    if (i < 3072) bqkv_s[i] = bqkv[i] * (i < 1024 ? SC2 : 1.0f);
    return;
  }
  const float* in;
  unsigned short* out;
  int N, K, n0, k0;
  float wscale = 1.0f;
  if (bid < 7168) {                         // Wqkv: (1024,3072) -> (3072,1024)
    int tt = bid - 4096;
    in = Wqkv; out = wqT; N = 3072; K = 1024;
    n0 = (tt % 96) * 32; k0 = (tt / 96) * 32;
    if (n0 < 1024) wscale = SC2;            // Q columns pre-scaled
  } else {                                  // Wout: (1024,1024) -> (1024,1024)
    int tt = bid - 7168;
    in = Wout; out = woT; N = 1024; K = 1024;
    n0 = (tt % 32) * 32; k0 = (tt / 32) * 32;
  }
  const int tx = tid & 31, ty = tid >> 5;   // 32 x 8
#pragma unroll
  for (int i = 0; i < 4; ++i)
    t[ty + i * 8][tx] = in[(size_t)(k0 + ty + i * 8) * N + n0 + tx];
  __syncthreads();
#pragma unroll
  for (int i = 0; i < 4; ++i)
    out[(size_t)(n0 + ty + i * 8) * K + k0 + tx] = f2bf(t[tx][ty + i * 8] * wscale);
}

// -------- big-tile bf16 GEMM: 256 x BN, 8 waves, BK=64, 2-buf 1-barrier ----
// C = A @ Bt^T + bias. Waves 4(M) x 2(N); wave tile 64 x BN/2. Grid must be
// 256 blocks (= 1/CU, 8 waves/CU). Dynamic LDS 2*(256+BN)*64*2B.
// Per iter: ONE __syncthreads -> stage(kt+1 -> buf^1) -> 2 k-halves of frag
// ds_reads + MFMA. XOR swizzle (slot ^= row&7) -> conflict-free.
// FUSE_VT: cols >= 2048 (V third of qkv) also written transposed.
// F32OUT: f32 C (out-projection); else bf16 C.
template <int BN, bool F32OUT, bool FUSE_VT>
__global__ __launch_bounds__(512) void k_gemmbig(const unsigned short* __restrict__ A,
                                                 const unsigned short* __restrict__ Bt,
                                                 const float* __restrict__ bias,
                                                 void* __restrict__ Cout,
                                                 unsigned short* __restrict__ vT,
                                                 int M, int N, int K) {
  constexpr int NI = BN / 32;               // B frags per wave
  constexpr int ACH = 32;                   // A chunks (256 rows / 8)
  constexpr int NCH = ACH + BN / 8;         // total 8-row chunks
  constexpr int ASZ = 256 * 64;             // ushorts per A buffer
  constexpr int BSZ = BN * 64;
  extern __shared__ unsigned short lds[];
  const int tid = threadIdx.x;
  const int lane = tid & 63, wid = tid >> 6;     // 8 waves
  const int wr = wid >> 1, wc = wid & 1;         // 4(M) x 2(N)
  const int g = lane >> 4, li = lane & 15;
  const int m0 = blockIdx.y * 256, n0 = blockIdx.x * BN;

  f32x4 acc[4][NI] = {};
  const int nkt = K >> 6;                   // BK=64
  const int r8 = lane >> 3, sp = lane & 7;

  auto Abuf = [&](int i) { return lds + i * ASZ; };
  auto Bbuf = [&](int i) { return lds + 2 * ASZ + i * BSZ; };

  auto stage = [&](int bufi, int kt) {
#pragma unroll
    for (int c = wid; c < NCH; c += 8) {
      if (c < ACH) {
        int row = c * 8 + r8;
        int sl = sp ^ (row & 7);
        gload_lds16(A + (size_t)(m0 + row) * K + kt * 64 + sl * 8,
                    Abuf(bufi) + c * 512);
      } else {
        int cc = c - ACH;
        int row = cc * 8 + r8;
        int sl = sp ^ (row & 7);
        gload_lds16(Bt + (size_t)(n0 + row) * K + kt * 64 + sl * 8,
                    Bbuf(bufi) + cc * 512);
      }
    }
  };

  stage(0, 0);
  for (int kt = 0; kt < nkt; ++kt) {
    __syncthreads();                        // tile-kt landed; buf^1 reads retired
    if (kt + 1 < nkt) stage((kt + 1) & 1, kt + 1);   // prefetch under compute
    const unsigned short* Ac = Abuf(kt & 1);
    const unsigned short* Bc = Bbuf(kt & 1);
#pragma unroll
    for (int h = 0; h < 2; ++h) {           // two k-halves of 32
      bf16x8 af[4], bfr[NI];
#pragma unroll
      for (int mi = 0; mi < 4; ++mi) {
        const int r = wr * 64 + mi * 16 + li;
        const int slot = (g + h * 4) ^ (r & 7);
        af[mi] = *(const bf16x8*)&Ac[r * 64 + slot * 8];
      }
#pragma unroll
      for (int ni = 0; ni < NI; ++ni) {
        const int r = wc * (BN / 2) + ni * 16 + li;
        const int slot = (g + h * 4) ^ (r & 7);
        bfr[ni] = *(const bf16x8*)&Bc[r * 64 + slot * 8];
      }
#pragma unroll
      for (int mi = 0; mi < 4; ++mi)
#pragma unroll
        for (int ni = 0; ni < NI; ++ni)
          acc[mi][ni] = __builtin_amdgcn_mfma_f32_16x16x32_bf16(af[mi], bfr[ni],
                                                                acc[mi][ni], 0, 0, 0);
    }
  }

  // epilogue: C/D layout col = li, row = g*4 + reg
  float bv[NI];
#pragma unroll
  for (int ni = 0; ni < NI; ++ni) bv[ni] = bias[n0 + wc * (BN / 2) + ni * 16 + li];
#pragma unroll
  for (int mi = 0; mi < 4; ++mi) {
#pragma unroll
    for (int ni = 0; ni < NI; ++ni) {
      const int col = n0 + wc * (BN / 2) + ni * 16 + li;
      const int row0 = m0 + wr * 64 + mi * 16 + g * 4;
      float v0 = acc[mi][ni][0] + bv[ni];
      float v1 = acc[mi][ni][1] + bv[ni];
      float v2 = acc[mi][ni][2] + bv[ni];
      float v3 = acc[mi][ni][3] + bv[ni];
      if (F32OUT) {
        float* C = (float*)Cout;
        C[(size_t)(row0 + 0) * N + col] = v0;
        C[(size_t)(row0 + 1) * N + col] = v1;
        C[(size_t)(row0 + 2) * N + col] = v2;
        C[(size_t)(row0 + 3) * N + col] = v3;
      } else {
        unsigned short* C = (unsigned short*)Cout;
        C[(size_t)(row0 + 0) * N + col] = f2bf(v0);
        C[(size_t)(row0 + 1) * N + col] = f2bf(v1);
        C[(size_t)(row0 + 2) * N + col] = f2bf(v2);
        C[(size_t)(row0 + 3) * N + col] = f2bf(v3);
      }
      if (FUSE_VT && col >= 2048) {         // V third: also write transposed
        const int b = row0 >> 11;
        const int s = row0 & 2047;
        u16x4 vv;
        vv[0] = f2bf(v0); vv[1] = f2bf(v1); vv[2] = f2bf(v2); vv[3] = f2bf(v3);
        *(u16x4*)&vT[(size_t)(b * 1024 + col - 2048) * 2048 + s] = vv;
      }
    }
  }
}

// ---------- windowed flash attention (static-max softmax, exp2) ------------
__global__ __launch_bounds__(256) void k_attn3(const unsigned short* __restrict__ qkv,
                                               const unsigned short* __restrict__ vT,
                                               unsigned short* __restrict__ attn) {
  __shared__ unsigned short Ks[2][64 * 64];
  __shared__ unsigned short Vs[2][64 * 64];
  __shared__ unsigned short Ps[64 * 88];
  const int tid = threadIdx.x, lane = tid & 63, wid = tid >> 6;
  const int g = lane >> 4, li = lane & 15;
  const int bh = blockIdx.y, b = bh >> 4, h = bh & 15;
  const int q0 = blockIdx.x * 64;
  const size_t rs = 3072;
  const unsigned short* qb = qkv + (size_t)b * 2048 * rs + h * 64;
  const unsigned short* kb = qb + 1024;
  const unsigned short* vb = vT + (size_t)bh * 64 * 2048;

  const int qrow = wid * 16 + li;
  const bf16x8 qf0 = *(const bf16x8*)(qb + (size_t)(q0 + qrow) * rs + (g << 3));
  const bf16x8 qf1 = *(const bf16x8*)(qb + (size_t)(q0 + qrow) * rs + 32 + (g << 3));

  const int tf = (blockIdx.x >= 4) ? 0 : (4 - (int)blockIdx.x);

  auto stage = [&](int bufi, int t) {
    const int j0 = q0 - 256 + t * 64;
    const int sl = (lane & 7) ^ ((lane >> 3) & 7);
#pragma unroll
    for (int j = 0; j < 2; ++j) {
      const int chunk = wid * 2 + j;
      const int row = chunk * 8 + (lane >> 3);
      gload_lds16(kb + (size_t)(j0 + row) * rs + sl * 8, &Ks[bufi][chunk * 512]);
      gload_lds16(vb + (size_t)row * 2048 + j0 + sl * 8, &Vs[bufi][chunk * 512]);
    }
  };

  f32x4 o[4] = {};
  float l_part[4] = {0.f, 0.f, 0.f, 0.f};

  stage(0, tf);
  int cur = 0;
  for (int t = tf; t < 5; ++t) {
    if (t + 1 < 5) {
      stage(cur ^ 1, t + 1);
      asm volatile("s_waitcnt vmcnt(4)" ::: "memory");
    } else {
      asm volatile("s_waitcnt vmcnt(0)" ::: "memory");
    }
    __builtin_amdgcn_sched_barrier(0);
    __builtin_amdgcn_s_barrier();
    __builtin_amdgcn_sched_barrier(0);

    const unsigned short* Kc = Ks[cur];
    const unsigned short* Vc = Vs[cur];

    f32x4 s[4];
#pragma unroll
    for (int ni = 0; ni < 4; ++ni) {
      const int kr = ni * 16 + li;
      const int sw = (kr & 7);
      bf16x8 kf0 = *(const bf16x8*)&Kc[kr * 64 + ((g ^ sw) << 3)];
      bf16x8 kf1 = *(const bf16x8*)&Kc[kr * 64 + (((4 + g) ^ sw) << 3)];
      f32x4 z = {};
      z = __builtin_amdgcn_mfma_f32_16x16x32_bf16(qf0, kf0, z, 0, 0, 0);
      z = __builtin_amdgcn_mfma_f32_16x16x32_bf16(qf1, kf1, z, 0, 0, 0);
      s[ni] = z;
    }
    const int rt = wid * 16 + g * 4;
#pragma unroll
    for (int ni = 0; ni < 4; ++ni) {
      int ct = ni * 16 + li;
#pragma unroll
      for (int reg = 0; reg < 4; ++reg) {
        float sv = s[ni][reg];
        if (t == 4 && ct > rt + reg) sv = -3e30f;   // causal
        if (t == 0 && ct < rt + reg) sv = -3e30f;   // window lower bound
        s[ni][reg] = sv;
      }
    }
    // static-max softmax: P = exp2(s' - 16); masked -> 0
#pragma unroll
    for (int reg = 0; reg < 4; ++reg) {
      float ps = 0.f;
#pragma unroll
      for (int ni = 0; ni < 4; ++ni) {
        float p = __builtin_exp2f(s[ni][reg] - 16.0f);
        ps += p;
        Ps[(wid * 16 + g * 4 + reg) * 88 + ni * 16 + li] = f2bf(p);
      }
      l_part[reg] += ps;
    }
    asm volatile("s_waitcnt lgkmcnt(0)" ::: "memory");
    __builtin_amdgcn_sched_barrier(0);
    const bf16x8 pf0 = *(const bf16x8*)&Ps[(wid * 16 + li) * 88 + (g << 3)];
    const bf16x8 pf1 = *(const bf16x8*)&Ps[(wid * 16 + li) * 88 + 32 + (g << 3)];
#pragma unroll
    for (int ni = 0; ni < 4; ++ni) {
      const int dr = ni * 16 + li;
      const int sw = (dr & 7);
      bf16x8 vf0 = *(const bf16x8*)&Vc[dr * 64 + ((g ^ sw) << 3)];
      bf16x8 vf1 = *(const bf16x8*)&Vc[dr * 64 + (((4 + g) ^ sw) << 3)];
      o[ni] = __builtin_amdgcn_mfma_f32_16x16x32_bf16(pf0, vf0, o[ni], 0, 0, 0);
      o[ni] = __builtin_amdgcn_mfma_f32_16x16x32_bf16(pf1, vf1, o[ni], 0, 0, 0);
    }
    __builtin_amdgcn_sched_barrier(0);
    __builtin_amdgcn_s_barrier();
    cur ^= 1;
  }

  float inv[4];
#pragma unroll
  for (int reg = 0; reg < 4; ++reg) {
    float L = l_part[reg];
    L += __shfl_xor(L, 1, 64);
    L += __shfl_xor(L, 2, 64);
    L += __shfl_xor(L, 4, 64);
    L += __shfl_xor(L, 8, 64);
    inv[reg] = 1.f / L;
  }
#pragma unroll
  for (int ni = 0; ni < 4; ++ni) {
#pragma unroll
    for (int reg = 0; reg < 4; ++reg) {
      size_t row = (size_t)b * 2048 + q0 + wid * 16 + g * 4 + reg;
      attn[row * 1024 + h * 64 + ni * 16 + li] = f2bf(o[ni][reg] * inv[reg]);
    }
  }
}

// ---------------------------------------------------------------------------
extern "C" void kernel_launch(void* const* d_in, const int* in_sizes, int n_in,
                              void* d_out, int out_size, void* d_ws, size_t ws_size,
                              hipStream_t stream) {
  const float* x    = (const float*)d_in[0];   // (4096, 1024)
  const float* Wqkv = (const float*)d_in[1];   // (1024, 3072)
  const float* bqkv = (const float*)d_in[2];   // (3072)
  const float* Wout = (const float*)d_in[3];   // (1024, 1024)
  const float* bout = (const float*)d_in[4];   // (1024)
  float* out = (float*)d_out;                  // (4096, 1024)

  uint8_t* ws = (uint8_t*)d_ws;
  unsigned short* xb    = (unsigned short*)(ws);              //  8.0 MB x bf16
  unsigned short* wqT   = (unsigned short*)(ws +  8388608);   //  6.0 MB Wqkv^T
  unsigned short* woT   = (unsigned short*)(ws + 14680064);   //  2.0 MB Wout^T
  unsigned short* qkvb  = (unsigned short*)(ws + 16777216);   // 24.0 MB qkv
  unsigned short* attnb = (unsigned short*)(ws + 41943040);   //  8.0 MB attn out
  unsigned short* vTb   = (unsigned short*)(ws + 50331648);   //  8.0 MB V^T
  float*          bqs   = (float*)(ws + 58720256);            // 12 KB scaled bias

  hipFuncSetAttribute((const void*)k_gemmbig<192, false, true>,
                      hipFuncAttributeMaxDynamicSharedMemorySize, 114688);
  hipFuncSetAttribute((const void*)k_gemmbig<64, true, false>,
                      hipFuncAttributeMaxDynamicSharedMemorySize, 81920);

  k_prep<<<8204, 256, 0, stream>>>(x, Wqkv, Wout, bqkv, xb, wqT, woT, bqs);
  k_gemmbig<192, false, true><<<dim3(3072 / 192, 4096 / 256), 512, 114688, stream>>>(
      xb, wqT, bqs, qkvb, vTb, 4096, 3072, 1024);
  k_attn3<<<dim3(2048 / 64, 32), 256, 0, stream>>>(qkvb, vTb, attnb);
  k_gemmbig<64, true, false><<<dim3(1024 / 64, 4096 / 256), 512, 81920, stream>>>(
      attnb, woT, bout, out, nullptr, 4096, 1024, 1024);
}

// Round 19
// 81.213 us; speedup vs baseline: 1.1316x; 1.0556x over previous
//
#include <hip/hip_runtime.h>
#include <stdint.h>

// ---------------------------------------------------------------------------
// WindowedAttn: x(2,2048,1024) f32 -> QKV proj -> windowed causal attn (W=256)
// -> out proj. bf16 MFMA pipeline, f32 in/out.
// Round 19: attn QBLK=128 with 8 PARALLEL waves (one 16-row strip each; not
// r6's serial sub-blocks): 512 blocks stage 6 tiles for 128 q-rows -> staging
// +barrier cost per q-row ~-40%. Waves 0-3 compute tiles 0-4, waves 4-7 tiles
// 1-5 (wave-uniform gate, barriers outside). gemms/prep = r18 champion.
// ---------------------------------------------------------------------------

typedef __attribute__((ext_vector_type(8))) short bf16x8;     // 8 bf16 (4 VGPR)
typedef __attribute__((ext_vector_type(4))) float f32x4;      // MFMA C/D
typedef __attribute__((ext_vector_type(4))) unsigned int u32x4;
typedef __attribute__((ext_vector_type(4))) unsigned short u16x4;

#define DEV static __device__ __forceinline__

#define SC2 0.18033688011112042f   // 0.125 * log2(e), folded into Wq + bq

DEV unsigned short f2bf(float f) {            // f32 -> bf16 RNE
  unsigned int u = __builtin_bit_cast(unsigned int, f);
  u += 0x7fffu + ((u >> 16) & 1u);
  return (unsigned short)(u >> 16);
}

DEV void gload_lds16(const void* g, void* l) { // 16B global -> LDS direct
  __builtin_amdgcn_global_load_lds((const __attribute__((address_space(1))) void*)g,
                                   (__attribute__((address_space(3))) void*)l,
                                   16, 0, 0);
}

// ------------- prep: x->bf16, Wqkv^T (Q cols pre-scaled), Wout^T, bias -----
__global__ __launch_bounds__(256) void k_prep(const float* __restrict__ x,
                                              const float* __restrict__ Wqkv,
                                              const float* __restrict__ Wout,
                                              const float* __restrict__ bqkv,
                                              unsigned short* __restrict__ xb,
                                              unsigned short* __restrict__ wqT,
                                              unsigned short* __restrict__ woT,
                                              float* __restrict__ bqkv_s) {
  __shared__ float t[32][33];
  const int bid = blockIdx.x, tid = threadIdx.x;
  if (bid < 4096) {
    int i = bid * 256 + tid;
    f32x4 v = ((const f32x4*)x)[i];
    u16x4 o;
    o[0] = f2bf(v[0]); o[1] = f2bf(v[1]); o[2] = f2bf(v[2]); o[3] = f2bf(v[3]);
    ((u16x4*)xb)[i] = o;
    return;
  }
  if (bid >= 8192) {                        // scaled bias (bq *= SC2)
    int i = (bid - 8192) * 256 + tid;
    if (i < 3072) bqkv_s[i] = bqkv[i] * (i < 1024 ? SC2 : 1.0f);
    return;
  }
  const float* in;
  unsigned short* out;
  int N, K, n0, k0;
  float wscale = 1.0f;
  if (bid < 7168) {                         // Wqkv: (1024,3072) -> (3072,1024)
    int tt = bid - 4096;
    in = Wqkv; out = wqT; N = 3072; K = 1024;
    n0 = (tt % 96) * 32; k0 = (tt / 96) * 32;
    if (n0 < 1024) wscale = SC2;            // Q columns pre-scaled
  } else {                                  // Wout: (1024,1024) -> (1024,1024)
    int tt = bid - 7168;
    in = Wout; out = woT; N = 1024; K = 1024;
    n0 = (tt % 32) * 32; k0 = (tt / 32) * 32;
  }
  const int tx = tid & 31, ty = tid >> 5;   // 32 x 8
#pragma unroll
  for (int i = 0; i < 4; ++i)
    t[ty + i * 8][tx] = in[(size_t)(k0 + ty + i * 8) * N + n0 + tx];
  __syncthreads();
#pragma unroll
  for (int i = 0; i < 4; ++i)
    out[(size_t)(n0 + ty + i * 8) * K + k0 + tx] = f2bf(t[tx][ty + i * 8] * wscale);
}

// -------- big-tile bf16 GEMM: 256 x BN, 8 waves, BK=64, 2-buf 1-barrier ----
// Grid must be 256 blocks (= 1/CU). Waves 4(M) x 2(N); wave tile 64 x BN/2.
// XOR swizzle (slot ^= row&7) -> conflict-free. FUSE_VT: cols >= 2048 also
// written transposed. F32OUT: f32 C (out-projection).
template <int BN, bool F32OUT, bool FUSE_VT>
__global__ __launch_bounds__(512) void k_gemmbig(const unsigned short* __restrict__ A,
                                                 const unsigned short* __restrict__ Bt,
                                                 const float* __restrict__ bias,
                                                 void* __restrict__ Cout,
                                                 unsigned short* __restrict__ vT,
                                                 int M, int N, int K) {
  constexpr int NI = BN / 32;               // B frags per wave
  constexpr int ACH = 32;                   // A chunks (256 rows / 8)
  constexpr int NCH = ACH + BN / 8;         // total 8-row chunks
  constexpr int ASZ = 256 * 64;             // ushorts per A buffer
  constexpr int BSZ = BN * 64;
  extern __shared__ unsigned short lds[];
  const int tid = threadIdx.x;
  const int lane = tid & 63, wid = tid >> 6;     // 8 waves
  const int wr = wid >> 1, wc = wid & 1;         // 4(M) x 2(N)
  const int g = lane >> 4, li = lane & 15;
  const int m0 = blockIdx.y * 256, n0 = blockIdx.x * BN;

  f32x4 acc[4][NI] = {};
  const int nkt = K >> 6;                   // BK=64
  const int r8 = lane >> 3, sp = lane & 7;

  auto Abuf = [&](int i) { return lds + i * ASZ; };
  auto Bbuf = [&](int i) { return lds + 2 * ASZ + i * BSZ; };

  auto stage = [&](int bufi, int kt) {
#pragma unroll
    for (int c = wid; c < NCH; c += 8) {
      if (c < ACH) {
        int row = c * 8 + r8;
        int sl = sp ^ (row & 7);
        gload_lds16(A + (size_t)(m0 + row) * K + kt * 64 + sl * 8,
                    Abuf(bufi) + c * 512);
      } else {
        int cc = c - ACH;
        int row = cc * 8 + r8;
        int sl = sp ^ (row & 7);
        gload_lds16(Bt + (size_t)(n0 + row) * K + kt * 64 + sl * 8,
                    Bbuf(bufi) + cc * 512);
      }
    }
  };

  stage(0, 0);
  for (int kt = 0; kt < nkt; ++kt) {
    __syncthreads();                        // tile-kt landed; buf^1 reads retired
    if (kt + 1 < nkt) stage((kt + 1) & 1, kt + 1);   // prefetch under compute
    const unsigned short* Ac = Abuf(kt & 1);
    const unsigned short* Bc = Bbuf(kt & 1);
#pragma unroll
    for (int h = 0; h < 2; ++h) {           // two k-halves of 32
      bf16x8 af[4], bfr[NI];
#pragma unroll
      for (int mi = 0; mi < 4; ++mi) {
        const int r = wr * 64 + mi * 16 + li;
        const int slot = (g + h * 4) ^ (r & 7);
        af[mi] = *(const bf16x8*)&Ac[r * 64 + slot * 8];
      }
#pragma unroll
      for (int ni = 0; ni < NI; ++ni) {
        const int r = wc * (BN / 2) + ni * 16 + li;
        const int slot = (g + h * 4) ^ (r & 7);
        bfr[ni] = *(const bf16x8*)&Bc[r * 64 + slot * 8];
      }
#pragma unroll
      for (int mi = 0; mi < 4; ++mi)
#pragma unroll
        for (int ni = 0; ni < NI; ++ni)
          acc[mi][ni] = __builtin_amdgcn_mfma_f32_16x16x32_bf16(af[mi], bfr[ni],
                                                                acc[mi][ni], 0, 0, 0);
    }
  }

  // epilogue: C/D layout col = li, row = g*4 + reg
  float bv[NI];
#pragma unroll
  for (int ni = 0; ni < NI; ++ni) bv[ni] = bias[n0 + wc * (BN / 2) + ni * 16 + li];
#pragma unroll
  for (int mi = 0; mi < 4; ++mi) {
#pragma unroll
    for (int ni = 0; ni < NI; ++ni) {
      const int col = n0 + wc * (BN / 2) + ni * 16 + li;
      const int row0 = m0 + wr * 64 + mi * 16 + g * 4;
      float v0 = acc[mi][ni][0] + bv[ni];
      float v1 = acc[mi][ni][1] + bv[ni];
      float v2 = acc[mi][ni][2] + bv[ni];
      float v3 = acc[mi][ni][3] + bv[ni];
      if (F32OUT) {
        float* C = (float*)Cout;
        C[(size_t)(row0 + 0) * N + col] = v0;
        C[(size_t)(row0 + 1) * N + col] = v1;
        C[(size_t)(row0 + 2) * N + col] = v2;
        C[(size_t)(row0 + 3) * N + col] = v3;
      } else {
        unsigned short* C = (unsigned short*)Cout;
        C[(size_t)(row0 + 0) * N + col] = f2bf(v0);
        C[(size_t)(row0 + 1) * N + col] = f2bf(v1);
        C[(size_t)(row0 + 2) * N + col] = f2bf(v2);
        C[(size_t)(row0 + 3) * N + col] = f2bf(v3);
      }
      if (FUSE_VT && col >= 2048) {         // V third: also write transposed
        const int b = row0 >> 11;
        const int s = row0 & 2047;
        u16x4 vv;
        vv[0] = f2bf(v0); vv[1] = f2bf(v1); vv[2] = f2bf(v2); vv[3] = f2bf(v3);
        *(u16x4*)&vT[(size_t)(b * 1024 + col - 2048) * 2048 + s] = vv;
      }
    }
  }
}

// ---- windowed flash attention: QBLK=128, 8 parallel waves, static-max -----
// qkv: (4096,3072) bf16 = [Q(pre-scaled)|K|V]; vT per (b,h): 64 d-rows x 2048.
// Block = (b,h,q-tile 128), 512 thr. Wave w owns q-rows w*16..w*16+15. Key
// range = 6 tiles of 64 (j0 = q0-256+t*64); waves 0-3 compute t in [0,4],
// waves 4-7 t in [1,5] (each exactly 5; gate wave-uniform, barriers outside).
// Masks: t==tfw -> ct < lr (window), t==tlw -> ct > lr (causal),
// lr = (w&3)*16 + g*4 + reg. Staging: 1 K-chunk + 1 V-chunk per wave (8 rows,
// XOR slot swizzle), dbuf with counted vmcnt(2). P = exp2(s'-16) static-max.
__global__ __launch_bounds__(512) void k_attn5(const unsigned short* __restrict__ qkv,
                                               const unsigned short* __restrict__ vT,
                                               unsigned short* __restrict__ attn) {
  __shared__ unsigned short Ks[2][64 * 64];
  __shared__ unsigned short Vs[2][64 * 64];
  __shared__ unsigned short Ps[128 * 88];    // wave-private 16-row regions
  const int tid = threadIdx.x, lane = tid & 63, wid = tid >> 6;
  const int g = lane >> 4, li = lane & 15;
  const int bh = blockIdx.y, b = bh >> 4, h = bh & 15;
  const int bx = blockIdx.x, q0 = bx * 128;
  const size_t rs = 3072;
  const unsigned short* qb = qkv + (size_t)b * 2048 * rs + h * 64;
  const unsigned short* kb = qb + 1024;
  const unsigned short* vb = vT + (size_t)bh * 64 * 2048;

  const int qrow = wid * 16 + li;            // 0..127 within block
  const bf16x8 qf0 = *(const bf16x8*)(qb + (size_t)(q0 + qrow) * rs + (g << 3));
  const bf16x8 qf1 = *(const bf16x8*)(qb + (size_t)(q0 + qrow) * rs + 32 + (g << 3));

  const int tf_blk = (bx >= 2) ? 0 : (4 - 2 * bx);  // first staged tile
  const int tfw = (wid >= 4) ? 1 : 0;               // wave's tile range
  const int tlw = tfw + 4;

  // stage tile t: per wave 1 K-chunk + 1 V-chunk of 8 rows (2 gloads/lane)
  auto stage = [&](int bufi, int t) {
    const int j0 = q0 - 256 + t * 64;
    const int row = wid * 8 + (lane >> 3);
    const int sl = (lane & 7) ^ (row & 7);
    gload_lds16(kb + (size_t)(j0 + row) * rs + sl * 8, &Ks[bufi][wid * 512]);
    gload_lds16(vb + (size_t)row * 2048 + j0 + sl * 8, &Vs[bufi][wid * 512]);
  };

  f32x4 o[4] = {};
  float l_part[4] = {0.f, 0.f, 0.f, 0.f};

  stage(0, tf_blk);
  int cur = 0;
  for (int t = tf_blk; t < 6; ++t) {
    if (t + 1 < 6) {
      stage(cur ^ 1, t + 1);
      asm volatile("s_waitcnt vmcnt(2)" ::: "memory");  // own tile-t loads landed
    } else {
      asm volatile("s_waitcnt vmcnt(0)" ::: "memory");
    }
    __builtin_amdgcn_sched_barrier(0);
    __builtin_amdgcn_s_barrier();
    __builtin_amdgcn_sched_barrier(0);

    if (t >= tfw && t <= tlw) {              // wave-uniform gate
      const unsigned short* Kc = Ks[cur];
      const unsigned short* Vc = Vs[cur];

      f32x4 s[4];
#pragma unroll
      for (int ni = 0; ni < 4; ++ni) {
        const int kr = ni * 16 + li;
        const int sw = (kr & 7);
        bf16x8 kf0 = *(const bf16x8*)&Kc[kr * 64 + ((g ^ sw) << 3)];
        bf16x8 kf1 = *(const bf16x8*)&Kc[kr * 64 + (((4 + g) ^ sw) << 3)];
        f32x4 z = {};
        z = __builtin_amdgcn_mfma_f32_16x16x32_bf16(qf0, kf0, z, 0, 0, 0);
        z = __builtin_amdgcn_mfma_f32_16x16x32_bf16(qf1, kf1, z, 0, 0, 0);
        s[ni] = z;
      }
      const int rt = (wid & 3) * 16 + g * 4; // local row lr = rt + reg
#pragma unroll
      for (int ni = 0; ni < 4; ++ni) {
        int ct = ni * 16 + li;
#pragma unroll
        for (int reg = 0; reg < 4; ++reg) {
          float sv = s[ni][reg];
          if (t == tlw && ct > rt + reg) sv = -3e30f;   // causal edge
          if (t == tfw && ct < rt + reg) sv = -3e30f;   // window edge
          s[ni][reg] = sv;
        }
      }
      // static-max softmax: P = exp2(s' - 16); masked -> 0
#pragma unroll
      for (int reg = 0; reg < 4; ++reg) {
        float ps = 0.f;
#pragma unroll
        for (int ni = 0; ni < 4; ++ni) {
          float p = __builtin_exp2f(s[ni][reg] - 16.0f);
          ps += p;
          Ps[(wid * 16 + g * 4 + reg) * 88 + ni * 16 + li] = f2bf(p);
        }
        l_part[reg] += ps;
      }
      // wave-private P round-trip (rule 18: explicit wait + sched fence)
      asm volatile("s_waitcnt lgkmcnt(0)" ::: "memory");
      __builtin_amdgcn_sched_barrier(0);
      const bf16x8 pf0 = *(const bf16x8*)&Ps[(wid * 16 + li) * 88 + (g << 3)];
      const bf16x8 pf1 = *(const bf16x8*)&Ps[(wid * 16 + li) * 88 + 32 + (g << 3)];
#pragma unroll
      for (int ni = 0; ni < 4; ++ni) {
        const int dr = ni * 16 + li;
        const int sw = (dr & 7);
        bf16x8 vf0 = *(const bf16x8*)&Vc[dr * 64 + ((g ^ sw) << 3)];
        bf16x8 vf1 = *(const bf16x8*)&Vc[dr * 64 + (((4 + g) ^ sw) << 3)];
        o[ni] = __builtin_amdgcn_mfma_f32_16x16x32_bf16(pf0, vf0, o[ni], 0, 0, 0);
        o[ni] = __builtin_amdgcn_mfma_f32_16x16x32_bf16(pf1, vf1, o[ni], 0, 0, 0);
      }
    }
    __builtin_amdgcn_sched_barrier(0);
    __builtin_amdgcn_s_barrier();            // all reads of buf[cur] retired (WAR)
    cur ^= 1;
  }

  float inv[4];
#pragma unroll
  for (int reg = 0; reg < 4; ++reg) {
    float L = l_part[reg];
    L += __shfl_xor(L, 1, 64);
    L += __shfl_xor(L, 2, 64);
    L += __shfl_xor(L, 4, 64);
    L += __shfl_xor(L, 8, 64);
    inv[reg] = 1.f / L;
  }
#pragma unroll
  for (int ni = 0; ni < 4; ++ni) {
#pragma unroll
    for (int reg = 0; reg < 4; ++reg) {
      size_t row = (size_t)b * 2048 + q0 + wid * 16 + g * 4 + reg;
      attn[row * 1024 + h * 64 + ni * 16 + li] = f2bf(o[ni][reg] * inv[reg]);
    }
  }
}

// ---------------------------------------------------------------------------
extern "C" void kernel_launch(void* const* d_in, const int* in_sizes, int n_in,
                              void* d_out, int out_size, void* d_ws, size_t ws_size,
                              hipStream_t stream) {
  const float* x    = (const float*)d_in[0];   // (4096, 1024)
  const float* Wqkv = (const float*)d_in[1];   // (1024, 3072)
  const float* bqkv = (const float*)d_in[2];   // (3072)
  const float* Wout = (const float*)d_in[3];   // (1024, 1024)
  const float* bout = (const float*)d_in[4];   // (1024)
  float* out = (float*)d_out;                  // (4096, 1024)

  uint8_t* ws = (uint8_t*)d_ws;
  unsigned short* xb    = (unsigned short*)(ws);              //  8.0 MB x bf16
  unsigned short* wqT   = (unsigned short*)(ws +  8388608);   //  6.0 MB Wqkv^T
  unsigned short* woT   = (unsigned short*)(ws + 14680064);   //  2.0 MB Wout^T
  unsigned short* qkvb  = (unsigned short*)(ws + 16777216);   // 24.0 MB qkv
  unsigned short* attnb = (unsigned short*)(ws + 41943040);   //  8.0 MB attn out
  unsigned short* vTb   = (unsigned short*)(ws + 50331648);   //  8.0 MB V^T
  float*          bqs   = (float*)(ws + 58720256);            // 12 KB scaled bias

  hipFuncSetAttribute((const void*)k_gemmbig<192, false, true>,
                      hipFuncAttributeMaxDynamicSharedMemorySize, 114688);
  hipFuncSetAttribute((const void*)k_gemmbig<64, true, false>,
                      hipFuncAttributeMaxDynamicSharedMemorySize, 81920);

  k_prep<<<8204, 256, 0, stream>>>(x, Wqkv, Wout, bqkv, xb, wqT, woT, bqs);
  k_gemmbig<192, false, true><<<dim3(3072 / 192, 4096 / 256), 512, 114688, stream>>>(
      xb, wqT, bqs, qkvb, vTb, 4096, 3072, 1024);
  k_attn5<<<dim3(2048 / 128, 32), 512, 0, stream>>>(qkvb, vTb, attnb);
  k_gemmbig<64, true, false><<<dim3(1024 / 64, 4096 / 256), 512, 81920, stream>>>(
      attnb, woT, bout, out, nullptr, 4096, 1024, 1024);
}